// Round 6
// baseline (446.241 us; speedup 1.0000x reference)
//
#include <hip/hip_runtime.h>
#include <hip/hip_cooperative_groups.h>

namespace cg = cooperative_groups;

#define IN_DIM 128
#define HID 64
#define MAXC 400            // >= ceil(N/256); N=100000 -> 391 coarse buckets
#define MAXB 512            // >= NBLK = ceil(E/EPB) = 391
#define EPB 4096
#define DPT 512             // degplace threads per block
#define G1CAP 6144          // LDS floats for k_gather1 staging (E[block]=4096, +32 sigma)

// ---- bf16 helpers (RNE) ----
static __device__ __forceinline__ unsigned short f2bf(float f) {
    unsigned u = __float_as_uint(f);
    u += 0x7FFF + ((u >> 16) & 1);
    return (unsigned short)(u >> 16);
}

typedef short bf16x8 __attribute__((ext_vector_type(8)));
typedef float f32x4 __attribute__((ext_vector_type(4)));

// =============== FUSED deterministic partition (cooperative) ===============
// phases: A hist -> B per-bucket scan -> C bucket-total scan -> D place tmp1
//         -> E per-bucket degree/dis/rowStart + place esrc
// Bodies are byte-equivalent to the proven 5-kernel chain (round 3).
__global__ __launch_bounds__(512) void k_partition(
    const int* __restrict__ src, const int* __restrict__ dst,
    int* __restrict__ hmat, int* __restrict__ bktTotal,
    int* __restrict__ coarseStart, float* __restrict__ dis,
    int* __restrict__ rowStart, int* __restrict__ esrc,
    int* __restrict__ tmp1, int N, int E, int NC, int NBLK)
{
    cg::grid_group grid = cg::this_grid();
    __shared__ int sA[MAXC];   // A: hist | D: bcnt | E: hist(256)
    __shared__ int sB[MAXC];   // D: bbase | E: cur(256)
    __shared__ int sc[512];    // B/C/E scans
    const int tid = threadIdx.x;
    const int blk = blockIdx.x;

    // ---- phase A: per-block bucket histogram -> hmat[blk][cb] ----
    if (blk < NBLK) {
        for (int i = tid; i < NC; i += 512) sA[i] = 0;
        __syncthreads();
        int e0 = blk * EPB, e1 = min(e0 + EPB, E);
        for (int e = e0 + tid; e < e1; e += 512) atomicAdd(&sA[dst[e] >> 8], 1);
        __syncthreads();
        for (int i = tid; i < NC; i += 512) hmat[blk * MAXC + i] = sA[i];
    }
    grid.sync();

    // ---- phase B: per-bucket exclusive scan across blocks (in-place) ----
    if (blk < NC) {
        int cb = blk;
        int v = (tid < NBLK) ? hmat[tid * MAXC + cb] : 0;
        sc[tid] = v;
        __syncthreads();
        for (int off = 1; off < 512; off <<= 1) {
            int a = (tid >= off) ? sc[tid - off] : 0;
            __syncthreads();
            sc[tid] += a;
            __syncthreads();
        }
        if (tid < NBLK) hmat[tid * MAXC + cb] = sc[tid] - v;
        if (tid == 511) bktTotal[cb] = sc[511];
    }
    grid.sync();

    // ---- phase C: single-block scan over bucket totals -> coarseStart ----
    if (blk == 0) {
        int v = (tid < NC) ? bktTotal[tid] : 0;
        sc[tid] = v;
        __syncthreads();
        for (int off = 1; off < 512; off <<= 1) {
            int a = (tid >= off) ? sc[tid - off] : 0;
            __syncthreads();
            sc[tid] += a;
            __syncthreads();
        }
        int excl = sc[tid] - v;
        if (tid < NC) coarseStart[tid] = excl;
        if (tid == NC - 1) coarseStart[NC] = excl + v;   // == E
        if (tid == 0) rowStart[N] = E;
    }
    grid.sync();

    // ---- phase D: deterministic placement into coarse-sorted tmp1 ----
    if (blk < NBLK) {
        for (int i = tid; i < NC; i += 512) {
            sA[i] = 0;
            sB[i] = coarseStart[i] + hmat[blk * MAXC + i];
        }
        __syncthreads();
        int e0 = blk * EPB, e1 = min(e0 + EPB, E);
        for (int e = e0 + tid; e < e1; e += 512) {
            int s = src[e], d = dst[e];
            int cb = d >> 8;
            int slot = sB[cb] + atomicAdd(&sA[cb], 1);
            tmp1[slot] = s | ((d & 255) << 17);
        }
    }
    grid.sync();

    // ---- phase E: per-bucket degree -> dis/rowStart, place into esrc ----
    if (blk < NC) {
        int cb = blk;
        int node0 = cb << 8;
        const int r0 = coarseStart[cb], r1 = coarseStart[cb + 1];
        if (tid < 256) sA[tid] = 0;
        __syncthreads();
        for (int i = r0 + tid; i < r1; i += 512)
            atomicAdd(&sA[((unsigned)tmp1[i]) >> 17], 1);
        __syncthreads();
        int v = 0;
        if (tid < 256) { v = sA[tid]; sc[tid] = v; }
        __syncthreads();
        for (int off = 1; off < 256; off <<= 1) {
            int a = 0;
            if (tid < 256 && tid >= off) a = sc[tid - off];
            __syncthreads();
            if (tid < 256) sc[tid] += a;
            __syncthreads();
        }
        if (tid < 256) {
            int myStart = r0 + sc[tid] - v;
            sB[tid] = myStart;
            int node = node0 + tid;
            if (node < N) {
                dis[node] = rsqrtf((float)v + 1.0f);
                rowStart[node] = myStart;
            }
        }
        __syncthreads();
        for (int i = r0 + tid; i < r1; i += 512) {
            int pk = tmp1[i];
            int dl = ((unsigned)pk) >> 17;
            int pos = atomicAdd(&sB[dl], 1);
            esrc[pos] = (pk & 0x1FFFF) << 7;     // byte offset of bf16 row
        }
    }
}

// =============== fallback: the original 5-kernel chain (round 3) ===============
__global__ __launch_bounds__(256) void k_hist2(const int* __restrict__ dst,
                                               int* __restrict__ hmat, int E, int NC) {
    __shared__ int h[MAXC];
    int tid = threadIdx.x, blk = blockIdx.x;
    for (int i = tid; i < NC; i += 256) h[i] = 0;
    __syncthreads();
    int e0 = blk * EPB, e1 = min(e0 + EPB, E);
    for (int e = e0 + tid; e < e1; e += 256) atomicAdd(&h[dst[e] >> 8], 1);
    __syncthreads();
    for (int i = tid; i < NC; i += 256) hmat[blk * MAXC + i] = h[i];
}

__global__ __launch_bounds__(512) void k_bktscan(int* __restrict__ hmat,
                                                 int* __restrict__ bktTotal,
                                                 int NBLK, int NC) {
    __shared__ int tmp[512];
    int cb = blockIdx.x;
    int t = threadIdx.x;
    int v = (t < NBLK) ? hmat[t * MAXC + cb] : 0;
    tmp[t] = v;
    __syncthreads();
    for (int off = 1; off < 512; off <<= 1) {
        int a = (t >= off) ? tmp[t - off] : 0;
        __syncthreads();
        tmp[t] += a;
        __syncthreads();
    }
    if (t < NBLK) hmat[t * MAXC + cb] = tmp[t] - v;
    if (t == 511) bktTotal[cb] = tmp[511];
}

__global__ __launch_bounds__(512) void k_cscan(const int* __restrict__ bktTotal,
                                               int* __restrict__ coarseStart,
                                               int* __restrict__ rowStart,
                                               int NC, int N, int E) {
    __shared__ int tmp[512];
    int t = threadIdx.x;
    int v = (t < NC) ? bktTotal[t] : 0;
    tmp[t] = v;
    __syncthreads();
    for (int off = 1; off < 512; off <<= 1) {
        int a = (t >= off) ? tmp[t - off] : 0;
        __syncthreads();
        tmp[t] += a;
        __syncthreads();
    }
    int excl = tmp[t] - v;
    if (t < NC) coarseStart[t] = excl;
    if (t == NC - 1) coarseStart[NC] = excl + v;
    if (t == 0) rowStart[N] = E;
}

__global__ __launch_bounds__(256) void k_part1(const int* __restrict__ src,
                                               const int* __restrict__ dst,
                                               const int* __restrict__ hmat,
                                               const int* __restrict__ coarseStart,
                                               int* __restrict__ tmp1,
                                               int E, int NC) {
    __shared__ int bcnt[MAXC];
    __shared__ int bbase[MAXC];
    int tid = threadIdx.x, blk = blockIdx.x;
    for (int i = tid; i < NC; i += 256) {
        bcnt[i] = 0;
        bbase[i] = coarseStart[i] + hmat[blk * MAXC + i];
    }
    __syncthreads();
    int e0 = blk * EPB, e1 = min(e0 + EPB, E);
    for (int e = e0 + tid; e < e1; e += 256) {
        int s = src[e], d = dst[e];
        int cb = d >> 8;
        int slot = bbase[cb] + atomicAdd(&bcnt[cb], 1);
        tmp1[slot] = s | ((d & 255) << 17);
    }
}

__global__ __launch_bounds__(DPT) void k_degplace(const int* __restrict__ tmp1,
                                                  const int* __restrict__ coarseStart,
                                                  float* __restrict__ dis,
                                                  int* __restrict__ rowStart,
                                                  int* __restrict__ esrc, int N) {
    __shared__ int hist[256];
    __shared__ int scn[256];
    __shared__ int cur[256];
    int tid = threadIdx.x;
    int cb = blockIdx.x;
    int node0 = cb << 8;
    const int r0 = coarseStart[cb], r1 = coarseStart[cb + 1];
    if (tid < 256) hist[tid] = 0;
    __syncthreads();
    for (int i = r0 + tid; i < r1; i += DPT)
        atomicAdd(&hist[((unsigned)tmp1[i]) >> 17], 1);
    __syncthreads();
    int v = 0;
    if (tid < 256) { v = hist[tid]; scn[tid] = v; }
    __syncthreads();
    for (int off = 1; off < 256; off <<= 1) {
        int a = 0;
        if (tid < 256 && tid >= off) a = scn[tid - off];
        __syncthreads();
        if (tid < 256) scn[tid] += a;
        __syncthreads();
    }
    if (tid < 256) {
        int myStart = r0 + scn[tid] - v;
        cur[tid] = myStart;
        int node = node0 + tid;
        if (node < N) {
            dis[node] = rsqrtf((float)v + 1.0f);
            rowStart[node] = myStart;
        }
    }
    __syncthreads();
    for (int i = r0 + tid; i < r1; i += DPT) {
        int pk = tmp1[i];
        int dl = ((unsigned)pk) >> 17;
        int pos = atomicAdd(&cur[dl], 1);
        esrc[pos] = (pk & 0x1FFFF) << 7;
    }
}

// ------- MFMA transform: Hbs[N,64] = bf16( (X[N,K] @ W[K,64]) * dis[row] ) -------
template <int K, typename T>
__global__ __launch_bounds__(256) void k_mmx(const T* __restrict__ X,
                                             const float* __restrict__ W,
                                             const float* __restrict__ dis,
                                             unsigned short* __restrict__ Hbs, int N) {
    constexpr int WP = K + 8;
    __shared__ unsigned short Wt[64 * WP];
    const int tid = threadIdx.x;
    for (int i = tid; i < K * 64; i += 256) {
        int k = i >> 6, n = i & 63;
        Wt[n * WP + k] = f2bf(W[i]);
    }
    __syncthreads();
    const int lane = tid & 63;
    const int m16 = lane & 15;
    const int quad = lane >> 4;
    const int rowBase = blockIdx.x * 64 + (tid >> 6) * 16;
    const int rowc = min(rowBase + m16, N - 1);

    f32x4 acc0 = {0.f, 0.f, 0.f, 0.f};
    f32x4 acc1 = acc0, acc2 = acc0, acc3 = acc0;
    const T* xrow = X + (size_t)rowc * K;
#pragma unroll
    for (int k0 = 0; k0 < K; k0 += 32) {
        bf16x8 af;
        if constexpr (sizeof(T) == 4) {
            const float* xp = (const float*)xrow + k0 + quad * 8;
            float4 xa = *(const float4*)xp;
            float4 xb = *(const float4*)(xp + 4);
            af[0] = (short)f2bf(xa.x); af[1] = (short)f2bf(xa.y);
            af[2] = (short)f2bf(xa.z); af[3] = (short)f2bf(xa.w);
            af[4] = (short)f2bf(xb.x); af[5] = (short)f2bf(xb.y);
            af[6] = (short)f2bf(xb.z); af[7] = (short)f2bf(xb.w);
        } else {
            af = *(const bf16x8*)((const unsigned short*)xrow + k0 + quad * 8);
        }
        const unsigned short* wp = &Wt[m16 * WP + k0 + quad * 8];
        bf16x8 b0 = *(const bf16x8*)(wp);
        bf16x8 b1 = *(const bf16x8*)(wp + 16 * WP);
        bf16x8 b2 = *(const bf16x8*)(wp + 32 * WP);
        bf16x8 b3 = *(const bf16x8*)(wp + 48 * WP);
        acc0 = __builtin_amdgcn_mfma_f32_16x16x32_bf16(af, b0, acc0, 0, 0, 0);
        acc1 = __builtin_amdgcn_mfma_f32_16x16x32_bf16(af, b1, acc1, 0, 0, 0);
        acc2 = __builtin_amdgcn_mfma_f32_16x16x32_bf16(af, b2, acc2, 0, 0, 0);
        acc3 = __builtin_amdgcn_mfma_f32_16x16x32_bf16(af, b3, acc3, 0, 0, 0);
    }
#pragma unroll
    for (int reg = 0; reg < 4; ++reg) {
        int r = rowBase + quad * 4 + reg;
        if (r < N) {
            float dsc = dis[r];
            unsigned short* hp = Hbs + (size_t)r * 64 + m16;
            hp[0]  = f2bf(acc0[reg] * dsc);
            hp[16] = f2bf(acc1[reg] * dsc);
            hp[32] = f2bf(acc2[reg] * dsc);
            hp[48] = f2bf(acc3[reg] * dsc);
        }
    }
}

// ------- gather-aggregate: quarter-wave (16 lanes) per node, dwordx2/lane -----
// Each quarter OWNS its node's edge-offset batches (shfl sources stay inside the
// quarter; quarter-uniform loop bounds -> all 16 lanes of an active quarter are
// active -> bpermute always reads active lanes). 8-deep independent-load cascade.
// MODE 1: out = relu row, stored bf16 (feeds bf16 mmx)
// MODE 2: relu row, dot with W3, write colS[i] = dot*dis and out[i] = dot*dis^2 + b3

#define BLO(d) __uint_as_float((d) << 16)
#define BHI(d) __uint_as_float((d) & 0xFFFF0000u)
#define ACC2(A, Q) { A.x += BLO((Q).x); A.y += BHI((Q).x);                     \
                     A.z += BLO((Q).y); A.w += BHI((Q).y); }

template <int MODE>
__global__ __launch_bounds__(256) void k_gather64(const unsigned short* __restrict__ Hbs,
                                                  const int* __restrict__ esrc,
                                                  const int* __restrict__ rowStart,
                                                  const float* __restrict__ dis,
                                                  const float* __restrict__ b,
                                                  unsigned short* __restrict__ outB,
                                                  const float* __restrict__ W3,
                                                  const float* __restrict__ b3,
                                                  float* __restrict__ colS,
                                                  float* __restrict__ outF,
                                                  int N) {
    int lane = threadIdx.x & 63;
    int c = lane & 15;          // 8B chunk of the 128B row
    int sub = lane >> 4;        // quarter index == node slot
    int qb = sub << 4;          // quarter's first lane (shfl base)
    int wave = (blockIdx.x * 256 + threadIdx.x) >> 6;
    int g0 = wave * 4;
    if (g0 >= N) return;
    const char* hb = (const char*)Hbs + c * 8;

    int rb = rowStart[min(g0 + lane, N)];      // wave fully active here
    int Rq  = __shfl(rb, sub, 64);             // this quarter's segment [Rq, Rq1)
    int Rq1 = __shfl(rb, sub + 1, 64);
    int n = g0 + sub;                          // this quarter's node
    int nc = min(n, N - 1);

    // self-loop seed: quarter's own row (h[n]*dis[n]); scaled by dis[n] later
    float4 a;
    {
        uint2 sd = *(const uint2*)(hb + ((size_t)nc << 7));
        a.x = BLO(sd.x); a.y = BHI(sd.x); a.z = BLO(sd.y); a.w = BHI(sd.y);
    }

    unsigned eoff = (Rq + c < Rq1) ? (unsigned)esrc[Rq + c] : 0u;
    for (int bb = Rq; bb < Rq1; bb += 16) {
        int cnt = min(16, Rq1 - bb);
        // prefetch next batch's offsets (independent of this batch's work)
        unsigned eoffN = (bb + 16 + c < Rq1) ? (unsigned)esrc[bb + 16 + c] : 0u;

        int j = 0;
        for (; j + 8 <= cnt; j += 8) {
            unsigned o0 = __shfl(eoff, qb + j + 0, 64);
            unsigned o1 = __shfl(eoff, qb + j + 1, 64);
            unsigned o2 = __shfl(eoff, qb + j + 2, 64);
            unsigned o3 = __shfl(eoff, qb + j + 3, 64);
            unsigned o4 = __shfl(eoff, qb + j + 4, 64);
            unsigned o5 = __shfl(eoff, qb + j + 5, 64);
            unsigned o6 = __shfl(eoff, qb + j + 6, 64);
            unsigned o7 = __shfl(eoff, qb + j + 7, 64);
            uint2 q0 = *(const uint2*)(hb + o0);
            uint2 q1 = *(const uint2*)(hb + o1);
            uint2 q2 = *(const uint2*)(hb + o2);
            uint2 q3 = *(const uint2*)(hb + o3);
            uint2 q4 = *(const uint2*)(hb + o4);
            uint2 q5 = *(const uint2*)(hb + o5);
            uint2 q6 = *(const uint2*)(hb + o6);
            uint2 q7 = *(const uint2*)(hb + o7);
            ACC2(a, q0) ACC2(a, q1) ACC2(a, q2) ACC2(a, q3)
            ACC2(a, q4) ACC2(a, q5) ACC2(a, q6) ACC2(a, q7)
        }
        if (j + 4 <= cnt) {
            unsigned o0 = __shfl(eoff, qb + j + 0, 64);
            unsigned o1 = __shfl(eoff, qb + j + 1, 64);
            unsigned o2 = __shfl(eoff, qb + j + 2, 64);
            unsigned o3 = __shfl(eoff, qb + j + 3, 64);
            uint2 q0 = *(const uint2*)(hb + o0);
            uint2 q1 = *(const uint2*)(hb + o1);
            uint2 q2 = *(const uint2*)(hb + o2);
            uint2 q3 = *(const uint2*)(hb + o3);
            ACC2(a, q0) ACC2(a, q1) ACC2(a, q2) ACC2(a, q3)
            j += 4;
        }
        if (j < cnt) {   // masked remainder 1..3 (slot 0 always valid)
            bool v1 = j + 1 < cnt, v2 = j + 2 < cnt;
            unsigned o0 = __shfl(eoff, qb + j, 64);
            unsigned o1 = __shfl(eoff, v1 ? qb + j + 1 : qb + j, 64);
            unsigned o2 = __shfl(eoff, v2 ? qb + j + 2 : qb + j, 64);
            uint2 q0 = *(const uint2*)(hb + o0);
            uint2 q1 = *(const uint2*)(hb + o1);
            uint2 q2 = *(const uint2*)(hb + o2);
            if (!v1) { q1.x = 0u; q1.y = 0u; }
            if (!v2) { q2.x = 0u; q2.y = 0u; }
            ACC2(a, q0) ACC2(a, q1) ACC2(a, q2)
        }
        eoff = eoffN;
    }

    // epilogue: each quarter finalizes its own node; no cross-sub reduction
    float ds = dis[nc];
    float4 bl = ((const float4*)b)[c];
    float4 v;
    v.x = fmaxf(a.x * ds + bl.x, 0.f);
    v.y = fmaxf(a.y * ds + bl.y, 0.f);
    v.z = fmaxf(a.z * ds + bl.z, 0.f);
    v.w = fmaxf(a.w * ds + bl.w, 0.f);

    if (MODE == 1) {
        uint2 pv;
        pv.x = (unsigned)f2bf(v.x) | ((unsigned)f2bf(v.y) << 16);
        pv.y = (unsigned)f2bf(v.z) | ((unsigned)f2bf(v.w) << 16);
        if (n < N) ((uint2*)outB)[(size_t)n * 16 + c] = pv;   // 512B/wave coalesced
    } else {
        float4 w3 = ((const float4*)W3)[c];
        float t = v.x * w3.x + v.y * w3.y + v.z * w3.z + v.w * w3.w;
        t += __shfl_xor(t, 1, 64);
        t += __shfl_xor(t, 2, 64);
        t += __shfl_xor(t, 4, 64);
        t += __shfl_xor(t, 8, 64);
        if (c == 0 && n < N) {
            colS[n] = t * ds;
            outF[n] = t * ds * ds + b3[0];
        }
    }
}

// layer-3 aggregation: stage block's colS values in LDS (parallel loads),
// then per-node serial sum out of LDS. out[i] += dis[i] * sum colS[esrc>>7]
__global__ __launch_bounds__(256) void k_gather1(const float* __restrict__ colS,
                                                 const int* __restrict__ esrc,
                                                 const int* __restrict__ rowStart,
                                                 const float* __restrict__ dis,
                                                 float* __restrict__ out, int N) {
    __shared__ float ls[G1CAP];
    int tid = threadIdx.x;
    int n0 = blockIdx.x * 256;
    int nEnd = min(n0 + 256, N);
    int r0 = rowStart[n0];
    int r1 = rowStart[nEnd];
    int cnt = r1 - r0;
    if (cnt <= G1CAP) {
        for (int i = tid; i < cnt; i += 256)
            ls[i] = colS[((unsigned)esrc[r0 + i]) >> 7];
        __syncthreads();
        int n = n0 + tid;
        if (n < N) {
            int a = rowStart[n] - r0, bnd = rowStart[n + 1] - r0;
            float acc = 0.0f;
            for (int e = a; e < bnd; ++e) acc += ls[e];
            out[n] += acc * dis[n];
        }
    } else {   // statistically unreachable fallback
        int n = n0 + tid;
        if (n < N) {
            int a = rowStart[n], bnd = rowStart[n + 1];
            float acc = 0.0f;
            for (int e = a; e < bnd; ++e) acc += colS[((unsigned)esrc[e]) >> 7];
            out[n] += acc * dis[n];
        }
    }
}

extern "C" void kernel_launch(void* const* d_in, const int* in_sizes, int n_in,
                              void* d_out, int out_size, void* d_ws, size_t ws_size,
                              hipStream_t stream) {
    const float* x  = (const float*)d_in[0];
    const int*   ei = (const int*)d_in[1];
    const float* W1 = (const float*)d_in[2];
    const float* b1 = (const float*)d_in[3];
    const float* W2 = (const float*)d_in[4];
    const float* b2 = (const float*)d_in[5];
    const float* W3 = (const float*)d_in[6];
    const float* b3 = (const float*)d_in[7];
    float* out = (float*)d_out;

    int N = in_sizes[0] / IN_DIM;     // 100000
    int E = in_sizes[1] / 2;          // 1600000
    const int* src = ei;
    const int* dst = ei + E;
    int NC = (N + 255) >> 8;          // 391 coarse buckets
    int NBLK = (E + EPB - 1) / EPB;   // 391 partition blocks

    // ---- workspace layout ----
    char* w = (char*)d_ws;
    auto alloc = [&](size_t bytes) {
        char* p = w;
        w += (bytes + 1023) & ~(size_t)1023;
        return p;
    };
    float*          dis        = (float*)alloc((size_t)N * 4);
    unsigned short* Hbs        = (unsigned short*)alloc((size_t)N * 64 * 2);
    unsigned short* Hb1        = (unsigned short*)alloc((size_t)N * 64 * 2);
    float*          colS       = (float*)alloc((size_t)N * 4);
    int*            rowStart   = (int*)alloc((size_t)(N + 1) * 4);
    int*            bktTotal   = (int*)alloc((size_t)MAXC * 4);
    int*            coarseStart= (int*)alloc((size_t)(MAXC + 1) * 4);
    int*            hmat       = (int*)alloc((size_t)MAXB * MAXC * 4);
    int*            esrc       = (int*)alloc((size_t)E * 4);
    int*            tmp1       = (int*)alloc((size_t)E * 4);

    const int NB_N  = (N + 255) / 256;
    const int NB_MX = (N + 63) / 64;                    // MFMA transform blocks
    const int NB_G4 = ((N + 3) / 4 * 64 + 255) / 256;   // 4 nodes per wave
    const int GP = (NBLK > NC) ? NBLK : NC;             // 391

    // ---- fused partition (cooperative); fallback to 5-kernel chain ----
    {
        void* args[] = {(void*)&src, (void*)&dst, (void*)&hmat, (void*)&bktTotal,
                        (void*)&coarseStart, (void*)&dis, (void*)&rowStart,
                        (void*)&esrc, (void*)&tmp1, (void*)&N, (void*)&E,
                        (void*)&NC, (void*)&NBLK};
        hipError_t cerr = hipLaunchCooperativeKernel((void*)k_partition,
                                                     dim3(GP), dim3(512),
                                                     args, 0, stream);
        if (cerr != hipSuccess) {
            (void)hipGetLastError();   // clear sticky error
            k_hist2<<<NBLK, 256, 0, stream>>>(dst, hmat, E, NC);
            k_bktscan<<<NC, 512, 0, stream>>>(hmat, bktTotal, NBLK, NC);
            k_cscan<<<1, 512, 0, stream>>>(bktTotal, coarseStart, rowStart, NC, N, E);
            k_part1<<<NBLK, 256, 0, stream>>>(src, dst, hmat, coarseStart, tmp1, E, NC);
            k_degplace<<<NC, DPT, 0, stream>>>(tmp1, coarseStart, dis, rowStart, esrc, N);
        }
    }

    // ---- layer 1: mmx fp32->bf16, gather -> bf16 rows ----
    k_mmx<IN_DIM, float><<<NB_MX, 256, 0, stream>>>(x, W1, dis, Hbs, N);
    k_gather64<1><<<NB_G4, 256, 0, stream>>>(Hbs, esrc, rowStart, dis, b1,
                                             Hb1, nullptr, nullptr, nullptr, nullptr, N);

    // ---- layer 2: mmx bf16 input, gather fused with W3 dot ----
    k_mmx<HID, unsigned short><<<NB_MX, 256, 0, stream>>>(Hb1, W2, dis, Hbs, N);
    k_gather64<2><<<NB_G4, 256, 0, stream>>>(Hbs, esrc, rowStart, dis, b2,
                                             nullptr, W3, b3, colS, out, N);

    // ---- layer 3 aggregation ----
    k_gather1<<<NB_N, 256, 0, stream>>>(colS, esrc, rowStart, dis, out, N);
}

// Round 7
// 233.250 us; speedup vs baseline: 1.9131x; 1.9131x over previous
//
#include <hip/hip_runtime.h>

#define IN_DIM 128
#define HID 64
#define MAXC 400            // >= ceil(N/256); N=100000 -> 391 coarse buckets
#define MAXB 512            // >= NBLK = ceil(E/EPB) = 391
#define EPB 4096
#define DPT 512             // degplace threads per block
#define G1CAP 6144          // LDS floats for k_gather1 staging (E[block]=4096, +32 sigma)

// ---- bf16 helpers (RNE) ----
static __device__ __forceinline__ unsigned short f2bf(float f) {
    unsigned u = __float_as_uint(f);
    u += 0x7FFF + ((u >> 16) & 1);
    return (unsigned short)(u >> 16);
}

typedef short bf16x8 __attribute__((ext_vector_type(8)));
typedef float f32x4 __attribute__((ext_vector_type(4)));

// ---- pass 0: per-block bucket histogram -> hmat[blk][cb] (coalesced row) ----
__global__ __launch_bounds__(256) void k_hist2(const int* __restrict__ dst,
                                               int* __restrict__ hmat, int E, int NC) {
    __shared__ int h[MAXC];
    int tid = threadIdx.x, blk = blockIdx.x;
    for (int i = tid; i < NC; i += 256) h[i] = 0;
    __syncthreads();
    int e0 = blk * EPB, e1 = min(e0 + EPB, E);
    for (int e = e0 + tid; e < e1; e += 256) atomicAdd(&h[dst[e] >> 8], 1);
    __syncthreads();
    for (int i = tid; i < NC; i += 256) hmat[blk * MAXC + i] = h[i];
}

// ---- per-bucket exclusive scan across blocks (in-place) + bucket totals ----
__global__ __launch_bounds__(512) void k_bktscan(int* __restrict__ hmat,
                                                 int* __restrict__ bktTotal,
                                                 int NBLK, int NC) {
    __shared__ int tmp[512];
    int cb = blockIdx.x;
    int t = threadIdx.x;
    int v = (t < NBLK) ? hmat[t * MAXC + cb] : 0;
    tmp[t] = v;
    __syncthreads();
    for (int off = 1; off < 512; off <<= 1) {
        int a = (t >= off) ? tmp[t - off] : 0;
        __syncthreads();
        tmp[t] += a;
        __syncthreads();
    }
    if (t < NBLK) hmat[t * MAXC + cb] = tmp[t] - v;   // exclusive prefix within bucket
    if (t == 511) bktTotal[cb] = tmp[511];
}

// ---- single-block scan over bucket totals -> coarseStart ----
__global__ __launch_bounds__(512) void k_cscan(const int* __restrict__ bktTotal,
                                               int* __restrict__ coarseStart,
                                               int* __restrict__ rowStart,
                                               int NC, int N, int E) {
    __shared__ int tmp[512];
    int t = threadIdx.x;
    int v = (t < NC) ? bktTotal[t] : 0;
    tmp[t] = v;
    __syncthreads();
    for (int off = 1; off < 512; off <<= 1) {
        int a = (t >= off) ? tmp[t - off] : 0;
        __syncthreads();
        tmp[t] += a;
        __syncthreads();
    }
    int excl = tmp[t] - v;
    if (t < NC) coarseStart[t] = excl;
    if (t == NC - 1) coarseStart[NC] = excl + v;   // == E
    if (t == 0) rowStart[N] = E;
}

// ---- pass 1: deterministic placement into dense coarse-sorted array ----
// tmp1[pos] = src | (dloc << 17); no global atomics.
__global__ __launch_bounds__(256) void k_part1(const int* __restrict__ src,
                                               const int* __restrict__ dst,
                                               const int* __restrict__ hmat,
                                               const int* __restrict__ coarseStart,
                                               int* __restrict__ tmp1,
                                               int E, int NC) {
    __shared__ int bcnt[MAXC];
    __shared__ int bbase[MAXC];
    int tid = threadIdx.x, blk = blockIdx.x;
    for (int i = tid; i < NC; i += 256) {
        bcnt[i] = 0;
        bbase[i] = coarseStart[i] + hmat[blk * MAXC + i];   // coalesced
    }
    __syncthreads();
    int e0 = blk * EPB, e1 = min(e0 + EPB, E);
    for (int e = e0 + tid; e < e1; e += 256) {
        int s = src[e], d = dst[e];
        int cb = d >> 8;
        int slot = bbase[cb] + atomicAdd(&bcnt[cb], 1);
        tmp1[slot] = s | ((d & 255) << 17);
    }
}

// ---- pass 2 (fused): per-bucket degree->dis/rowStart, then place into CSR ----
// esrc holds BYTE offsets (s*128) for the gather's addressing.
__global__ __launch_bounds__(DPT) void k_degplace(const int* __restrict__ tmp1,
                                                  const int* __restrict__ coarseStart,
                                                  float* __restrict__ dis,
                                                  int* __restrict__ rowStart,
                                                  int* __restrict__ esrc, int N) {
    __shared__ int hist[256];
    __shared__ int scn[256];
    __shared__ int cur[256];
    int tid = threadIdx.x;
    int cb = blockIdx.x;
    int node0 = cb << 8;
    const int r0 = coarseStart[cb], r1 = coarseStart[cb + 1];
    if (tid < 256) hist[tid] = 0;
    __syncthreads();
    for (int i = r0 + tid; i < r1; i += DPT)
        atomicAdd(&hist[((unsigned)tmp1[i]) >> 17], 1);
    __syncthreads();
    int v = 0;
    if (tid < 256) { v = hist[tid]; scn[tid] = v; }
    __syncthreads();
    for (int off = 1; off < 256; off <<= 1) {
        int a = 0;
        if (tid < 256 && tid >= off) a = scn[tid - off];
        __syncthreads();
        if (tid < 256) scn[tid] += a;
        __syncthreads();
    }
    if (tid < 256) {
        int myStart = r0 + scn[tid] - v;
        cur[tid] = myStart;
        int node = node0 + tid;
        if (node < N) {
            dis[node] = rsqrtf((float)v + 1.0f);
            rowStart[node] = myStart;
        }
    }
    __syncthreads();
    for (int i = r0 + tid; i < r1; i += DPT) {
        int pk = tmp1[i];
        int dl = ((unsigned)pk) >> 17;
        int pos = atomicAdd(&cur[dl], 1);
        esrc[pos] = (pk & 0x1FFFF) << 7;     // byte offset of bf16 row
    }
}

// ------- MFMA transform: Hbs[N,64] = bf16( (X[N,K] @ W[K,64]) * dis[row] ) -------
template <int K, typename T>
__global__ __launch_bounds__(256) void k_mmx(const T* __restrict__ X,
                                             const float* __restrict__ W,
                                             const float* __restrict__ dis,
                                             unsigned short* __restrict__ Hbs, int N) {
    constexpr int WP = K + 8;
    __shared__ unsigned short Wt[64 * WP];
    const int tid = threadIdx.x;
    for (int i = tid; i < K * 64; i += 256) {
        int k = i >> 6, n = i & 63;
        Wt[n * WP + k] = f2bf(W[i]);
    }
    __syncthreads();
    const int lane = tid & 63;
    const int m16 = lane & 15;
    const int quad = lane >> 4;
    const int rowBase = blockIdx.x * 64 + (tid >> 6) * 16;
    const int rowc = min(rowBase + m16, N - 1);

    f32x4 acc0 = {0.f, 0.f, 0.f, 0.f};
    f32x4 acc1 = acc0, acc2 = acc0, acc3 = acc0;
    const T* xrow = X + (size_t)rowc * K;
#pragma unroll
    for (int k0 = 0; k0 < K; k0 += 32) {
        bf16x8 af;
        if constexpr (sizeof(T) == 4) {
            const float* xp = (const float*)xrow + k0 + quad * 8;
            float4 xa = *(const float4*)xp;
            float4 xb = *(const float4*)(xp + 4);
            af[0] = (short)f2bf(xa.x); af[1] = (short)f2bf(xa.y);
            af[2] = (short)f2bf(xa.z); af[3] = (short)f2bf(xa.w);
            af[4] = (short)f2bf(xb.x); af[5] = (short)f2bf(xb.y);
            af[6] = (short)f2bf(xb.z); af[7] = (short)f2bf(xb.w);
        } else {
            af = *(const bf16x8*)((const unsigned short*)xrow + k0 + quad * 8);
        }
        const unsigned short* wp = &Wt[m16 * WP + k0 + quad * 8];
        bf16x8 b0 = *(const bf16x8*)(wp);
        bf16x8 b1 = *(const bf16x8*)(wp + 16 * WP);
        bf16x8 b2 = *(const bf16x8*)(wp + 32 * WP);
        bf16x8 b3 = *(const bf16x8*)(wp + 48 * WP);
        acc0 = __builtin_amdgcn_mfma_f32_16x16x32_bf16(af, b0, acc0, 0, 0, 0);
        acc1 = __builtin_amdgcn_mfma_f32_16x16x32_bf16(af, b1, acc1, 0, 0, 0);
        acc2 = __builtin_amdgcn_mfma_f32_16x16x32_bf16(af, b2, acc2, 0, 0, 0);
        acc3 = __builtin_amdgcn_mfma_f32_16x16x32_bf16(af, b3, acc3, 0, 0, 0);
    }
#pragma unroll
    for (int reg = 0; reg < 4; ++reg) {
        int r = rowBase + quad * 4 + reg;
        if (r < N) {
            float dsc = dis[r];
            unsigned short* hp = Hbs + (size_t)r * 64 + m16;
            hp[0]  = f2bf(acc0[reg] * dsc);
            hp[16] = f2bf(acc1[reg] * dsc);
            hp[32] = f2bf(acc2[reg] * dsc);
            hp[48] = f2bf(acc3[reg] * dsc);
        }
    }
}

// ------- gather-aggregate: OCTET (8 lanes) per node, uint4 (16B) per lane -----
// Each octet's 8 lanes cover the full 128B row; per wave-instruction 8 edges x
// 128B = 1KB in flight (2x the quarter scheme), and load+shuffle instruction
// count per edge is halved. Each octet OWNS its batches (lane c of octet o
// loads esrc[Rq + bb + c]); loop bounds are octet-uniform and shfl sources stay
// inside the octet [8o, 8o+8) -> bpermute only reads active lanes.
// MODE 1: out = relu row, stored bf16 (feeds bf16 mmx)
// MODE 2: relu row, dot with W3, write colS[i] = dot*dis and out[i] = dot*dis^2 + b3

#define BLO(d) __uint_as_float((d) << 16)
#define BHI(d) __uint_as_float((d) & 0xFFFF0000u)
#define ACC4(L, H, Q) { L.x += BLO((Q).x); L.y += BHI((Q).x);                  \
                        L.z += BLO((Q).y); L.w += BHI((Q).y);                  \
                        H.x += BLO((Q).z); H.y += BHI((Q).z);                  \
                        H.z += BLO((Q).w); H.w += BHI((Q).w); }

template <int MODE>
__global__ __launch_bounds__(256) void k_gather64(const unsigned short* __restrict__ Hbs,
                                                  const int* __restrict__ esrc,
                                                  const int* __restrict__ rowStart,
                                                  const float* __restrict__ dis,
                                                  const float* __restrict__ b,
                                                  unsigned short* __restrict__ outB,
                                                  const float* __restrict__ W3,
                                                  const float* __restrict__ b3,
                                                  float* __restrict__ colS,
                                                  float* __restrict__ outF,
                                                  int N) {
    int lane = threadIdx.x & 63;
    int c = lane & 7;           // 16B chunk of the 128B row
    int oct = lane >> 3;        // octet index == node slot (0..7)
    int ob = oct << 3;          // octet's first lane (shfl base)
    int wave = (blockIdx.x * 256 + threadIdx.x) >> 6;
    int g0 = wave * 8;
    if (g0 >= N) return;
    const char* hb = (const char*)Hbs + c * 16;

    int rb = rowStart[min(g0 + lane, N)];      // lanes 0..8 give the 9 bounds
    int Rq  = __shfl(rb, oct, 64);             // this octet's segment [Rq, Rq1)
    int Rq1 = __shfl(rb, oct + 1, 64);
    int n = g0 + oct;                          // this octet's node
    int nc = min(n, N - 1);

    // self-loop seed: octet's own row (h[n]*dis[n]); scaled by dis[n] later
    float4 aL, aH;
    {
        uint4 sd = *(const uint4*)(hb + ((size_t)nc << 7));
        aL.x = BLO(sd.x); aL.y = BHI(sd.x); aL.z = BLO(sd.y); aL.w = BHI(sd.y);
        aH.x = BLO(sd.z); aH.y = BHI(sd.z); aH.z = BLO(sd.w); aH.w = BHI(sd.w);
    }

    unsigned eoff = (Rq + c < Rq1) ? (unsigned)esrc[Rq + c] : 0u;
    for (int bb = Rq; bb < Rq1; bb += 8) {
        int cnt = min(8, Rq1 - bb);
        // prefetch next batch's offsets (independent of this batch's work)
        unsigned eoffN = (bb + 8 + c < Rq1) ? (unsigned)esrc[bb + 8 + c] : 0u;

        if (cnt == 8) {   // full batch: one 8-deep 16B cascade (128B/lane in flight)
            unsigned o0 = __shfl(eoff, ob + 0, 64);
            unsigned o1 = __shfl(eoff, ob + 1, 64);
            unsigned o2 = __shfl(eoff, ob + 2, 64);
            unsigned o3 = __shfl(eoff, ob + 3, 64);
            unsigned o4 = __shfl(eoff, ob + 4, 64);
            unsigned o5 = __shfl(eoff, ob + 5, 64);
            unsigned o6 = __shfl(eoff, ob + 6, 64);
            unsigned o7 = __shfl(eoff, ob + 7, 64);
            uint4 q0 = *(const uint4*)(hb + o0);
            uint4 q1 = *(const uint4*)(hb + o1);
            uint4 q2 = *(const uint4*)(hb + o2);
            uint4 q3 = *(const uint4*)(hb + o3);
            uint4 q4 = *(const uint4*)(hb + o4);
            uint4 q5 = *(const uint4*)(hb + o5);
            uint4 q6 = *(const uint4*)(hb + o6);
            uint4 q7 = *(const uint4*)(hb + o7);
            ACC4(aL, aH, q0) ACC4(aL, aH, q1) ACC4(aL, aH, q2) ACC4(aL, aH, q3)
            ACC4(aL, aH, q4) ACC4(aL, aH, q5) ACC4(aL, aH, q6) ACC4(aL, aH, q7)
        } else {
            int j = 0;
            if (j + 4 <= cnt) {
                unsigned o0 = __shfl(eoff, ob + j + 0, 64);
                unsigned o1 = __shfl(eoff, ob + j + 1, 64);
                unsigned o2 = __shfl(eoff, ob + j + 2, 64);
                unsigned o3 = __shfl(eoff, ob + j + 3, 64);
                uint4 q0 = *(const uint4*)(hb + o0);
                uint4 q1 = *(const uint4*)(hb + o1);
                uint4 q2 = *(const uint4*)(hb + o2);
                uint4 q3 = *(const uint4*)(hb + o3);
                ACC4(aL, aH, q0) ACC4(aL, aH, q1) ACC4(aL, aH, q2) ACC4(aL, aH, q3)
                j += 4;
            }
            if (j < cnt) {   // masked remainder 1..3 (slot 0 always valid)
                bool v1 = j + 1 < cnt, v2 = j + 2 < cnt;
                unsigned o0 = __shfl(eoff, ob + j, 64);
                unsigned o1 = __shfl(eoff, v1 ? ob + j + 1 : ob + j, 64);
                unsigned o2 = __shfl(eoff, v2 ? ob + j + 2 : ob + j, 64);
                uint4 q0 = *(const uint4*)(hb + o0);
                uint4 q1 = *(const uint4*)(hb + o1);
                uint4 q2 = *(const uint4*)(hb + o2);
                if (!v1) { q1.x = q1.y = q1.z = q1.w = 0u; }
                if (!v2) { q2.x = q2.y = q2.z = q2.w = 0u; }
                ACC4(aL, aH, q0) ACC4(aL, aH, q1) ACC4(aL, aH, q2)
            }
        }
        eoff = eoffN;
    }

    // epilogue: each octet finalizes its own node; no cross-octet reduction
    float ds = dis[nc];
    float4 bL = ((const float4*)b)[2 * c];
    float4 bH = ((const float4*)b)[2 * c + 1];
    float4 vL, vH;
    vL.x = fmaxf(aL.x * ds + bL.x, 0.f);
    vL.y = fmaxf(aL.y * ds + bL.y, 0.f);
    vL.z = fmaxf(aL.z * ds + bL.z, 0.f);
    vL.w = fmaxf(aL.w * ds + bL.w, 0.f);
    vH.x = fmaxf(aH.x * ds + bH.x, 0.f);
    vH.y = fmaxf(aH.y * ds + bH.y, 0.f);
    vH.z = fmaxf(aH.z * ds + bH.z, 0.f);
    vH.w = fmaxf(aH.w * ds + bH.w, 0.f);

    if (MODE == 1) {
        uint4 pv;
        pv.x = (unsigned)f2bf(vL.x) | ((unsigned)f2bf(vL.y) << 16);
        pv.y = (unsigned)f2bf(vL.z) | ((unsigned)f2bf(vL.w) << 16);
        pv.z = (unsigned)f2bf(vH.x) | ((unsigned)f2bf(vH.y) << 16);
        pv.w = (unsigned)f2bf(vH.z) | ((unsigned)f2bf(vH.w) << 16);
        if (n < N) ((uint4*)outB)[(size_t)n * 8 + c] = pv;   // 128B/row coalesced
    } else {
        float4 wL = ((const float4*)W3)[2 * c];
        float4 wH = ((const float4*)W3)[2 * c + 1];
        float t = vL.x * wL.x + vL.y * wL.y + vL.z * wL.z + vL.w * wL.w
                + vH.x * wH.x + vH.y * wH.y + vH.z * wH.z + vH.w * wH.w;
        t += __shfl_xor(t, 1, 64);
        t += __shfl_xor(t, 2, 64);
        t += __shfl_xor(t, 4, 64);
        if (c == 0 && n < N) {
            colS[n] = t * ds;
            outF[n] = t * ds * ds + b3[0];
        }
    }
}

// layer-3 aggregation: stage block's colS values in LDS (parallel loads),
// then per-node serial sum out of LDS. out[i] += dis[i] * sum colS[esrc>>7]
__global__ __launch_bounds__(256) void k_gather1(const float* __restrict__ colS,
                                                 const int* __restrict__ esrc,
                                                 const int* __restrict__ rowStart,
                                                 const float* __restrict__ dis,
                                                 float* __restrict__ out, int N) {
    __shared__ float ls[G1CAP];
    int tid = threadIdx.x;
    int n0 = blockIdx.x * 256;
    int nEnd = min(n0 + 256, N);
    int r0 = rowStart[n0];
    int r1 = rowStart[nEnd];
    int cnt = r1 - r0;
    if (cnt <= G1CAP) {
        for (int i = tid; i < cnt; i += 256)
            ls[i] = colS[((unsigned)esrc[r0 + i]) >> 7];
        __syncthreads();
        int n = n0 + tid;
        if (n < N) {
            int a = rowStart[n] - r0, bnd = rowStart[n + 1] - r0;
            float acc = 0.0f;
            for (int e = a; e < bnd; ++e) acc += ls[e];
            out[n] += acc * dis[n];
        }
    } else {   // statistically unreachable fallback
        int n = n0 + tid;
        if (n < N) {
            int a = rowStart[n], bnd = rowStart[n + 1];
            float acc = 0.0f;
            for (int e = a; e < bnd; ++e) acc += colS[((unsigned)esrc[e]) >> 7];
            out[n] += acc * dis[n];
        }
    }
}

extern "C" void kernel_launch(void* const* d_in, const int* in_sizes, int n_in,
                              void* d_out, int out_size, void* d_ws, size_t ws_size,
                              hipStream_t stream) {
    const float* x  = (const float*)d_in[0];
    const int*   ei = (const int*)d_in[1];
    const float* W1 = (const float*)d_in[2];
    const float* b1 = (const float*)d_in[3];
    const float* W2 = (const float*)d_in[4];
    const float* b2 = (const float*)d_in[5];
    const float* W3 = (const float*)d_in[6];
    const float* b3 = (const float*)d_in[7];
    float* out = (float*)d_out;

    const int N = in_sizes[0] / IN_DIM;     // 100000
    const int E = in_sizes[1] / 2;          // 1600000
    const int* src = ei;
    const int* dst = ei + E;
    const int NC = (N + 255) >> 8;          // 391 coarse buckets
    const int NBLK = (E + EPB - 1) / EPB;   // 391 partition blocks

    // ---- workspace layout ----
    char* w = (char*)d_ws;
    auto alloc = [&](size_t bytes) {
        char* p = w;
        w += (bytes + 1023) & ~(size_t)1023;
        return p;
    };
    float*          dis        = (float*)alloc((size_t)N * 4);
    unsigned short* Hbs        = (unsigned short*)alloc((size_t)N * 64 * 2);
    unsigned short* Hb1        = (unsigned short*)alloc((size_t)N * 64 * 2);
    float*          colS       = (float*)alloc((size_t)N * 4);
    int*            rowStart   = (int*)alloc((size_t)(N + 1) * 4);
    int*            bktTotal   = (int*)alloc((size_t)MAXC * 4);
    int*            coarseStart= (int*)alloc((size_t)(MAXC + 1) * 4);
    int*            hmat       = (int*)alloc((size_t)MAXB * MAXC * 4);
    int*            esrc       = (int*)alloc((size_t)E * 4 + 1024);
    int*            tmp1       = (int*)alloc((size_t)E * 4);

    const int NB_N  = (N + 255) / 256;
    const int NB_MX = (N + 63) / 64;                    // MFMA transform blocks
    const int NB_G8 = (((N + 7) / 8) * 64 + 255) / 256; // 8 nodes per wave

    // ---- deterministic partition (no global atomics, no memset) ----
    k_hist2<<<NBLK, 256, 0, stream>>>(dst, hmat, E, NC);
    k_bktscan<<<NC, 512, 0, stream>>>(hmat, bktTotal, NBLK, NC);
    k_cscan<<<1, 512, 0, stream>>>(bktTotal, coarseStart, rowStart, NC, N, E);
    k_part1<<<NBLK, 256, 0, stream>>>(src, dst, hmat, coarseStart, tmp1, E, NC);
    k_degplace<<<NC, DPT, 0, stream>>>(tmp1, coarseStart, dis, rowStart, esrc, N);

    // ---- layer 1: mmx fp32->bf16, gather -> bf16 rows ----
    k_mmx<IN_DIM, float><<<NB_MX, 256, 0, stream>>>(x, W1, dis, Hbs, N);
    k_gather64<1><<<NB_G8, 256, 0, stream>>>(Hbs, esrc, rowStart, dis, b1,
                                             Hb1, nullptr, nullptr, nullptr, nullptr, N);

    // ---- layer 2: mmx bf16 input, gather fused with W3 dot ----
    k_mmx<HID, unsigned short><<<NB_MX, 256, 0, stream>>>(Hb1, W2, dis, Hbs, N);
    k_gather64<2><<<NB_G8, 256, 0, stream>>>(Hbs, esrc, rowStart, dis, b2,
                                             nullptr, W3, b3, colS, out, N);

    // ---- layer 3 aggregation ----
    k_gather1<<<NB_N, 256, 0, stream>>>(colS, esrc, rowStart, dis, out, N);
}

// Round 9
// 229.830 us; speedup vs baseline: 1.9416x; 1.0149x over previous
//
#include <hip/hip_runtime.h>

#define IN_DIM 128
#define HID 64
#define MAXC 400            // >= ceil(N/256); N=100000 -> 391 coarse buckets
#define MAXB 512            // >= NBLK = ceil(E/EPB) = 391
#define EPB 4096
#define DPT 512             // degplace threads per block
#define G1CAP 6144          // LDS floats for k_gather1 staging (E[block]=4096, +32 sigma)

// ---- bf16 helpers (RNE) ----
static __device__ __forceinline__ unsigned short f2bf(float f) {
    unsigned u = __float_as_uint(f);
    u += 0x7FFF + ((u >> 16) & 1);
    return (unsigned short)(u >> 16);
}

typedef short bf16x8 __attribute__((ext_vector_type(8)));
typedef float f32x4 __attribute__((ext_vector_type(4)));

// ---- pass 0: per-block bucket histogram -> hmat[blk][cb]; blk0 zeroes ctr ----
__global__ __launch_bounds__(256) void k_hist2(const int* __restrict__ dst,
                                               int* __restrict__ hmat,
                                               int* __restrict__ ctr, int E, int NC) {
    __shared__ int h[MAXC];
    int tid = threadIdx.x, blk = blockIdx.x;
    if (blk == 0 && tid == 0) ctr[0] = 0;
    for (int i = tid; i < NC; i += 256) h[i] = 0;
    __syncthreads();
    int e0 = blk * EPB, e1 = min(e0 + EPB, E);
    for (int e = e0 + tid; e < e1; e += 256) atomicAdd(&h[dst[e] >> 8], 1);
    __syncthreads();
    for (int i = tid; i < NC; i += 256) hmat[blk * MAXC + i] = h[i];
}

// ---- per-bucket exclusive scan across blocks + (last block) bucket-total scan ----
// Cross-block comms via device-scope atomics only (coherence point), per G16.
__global__ __launch_bounds__(512) void k_bktscan(int* __restrict__ hmat,
                                                 int* __restrict__ bktTotal,
                                                 int* __restrict__ ctr,
                                                 int* __restrict__ coarseStart,
                                                 int* __restrict__ rowStart,
                                                 int NBLK, int NC, int N, int E) {
    __shared__ int tmp[512];
    __shared__ int lastFlag;
    int cb = blockIdx.x;
    int t = threadIdx.x;
    int v = (t < NBLK) ? hmat[t * MAXC + cb] : 0;
    tmp[t] = v;
    __syncthreads();
    for (int off = 1; off < 512; off <<= 1) {
        int a = (t >= off) ? tmp[t - off] : 0;
        __syncthreads();
        tmp[t] += a;
        __syncthreads();
    }
    if (t < NBLK) hmat[t * MAXC + cb] = tmp[t] - v;   // exclusive prefix within bucket
    if (t == 511) atomicExch(&bktTotal[cb], tmp[511]); // coherence-point publish
    __syncthreads();                                   // drains the atomic (vmcnt)
    if (t == 0) lastFlag = (atomicAdd(ctr, 1) == (int)gridDim.x - 1);
    __syncthreads();
    if (!lastFlag) return;
    // last arriving block: scan bucket totals -> coarseStart
    int v2 = (t < NC) ? atomicAdd(&bktTotal[t], 0) : 0;  // coherence-point read
    tmp[t] = v2;
    __syncthreads();
    for (int off = 1; off < 512; off <<= 1) {
        int a = (t >= off) ? tmp[t - off] : 0;
        __syncthreads();
        tmp[t] += a;
        __syncthreads();
    }
    int excl = tmp[t] - v2;
    if (t < NC) coarseStart[t] = excl;
    if (t == NC - 1) coarseStart[NC] = excl + v2;   // == E
    if (t == 0) rowStart[N] = E;
}

// ---- pass 1: deterministic placement into dense coarse-sorted array ----
__global__ __launch_bounds__(256) void k_part1(const int* __restrict__ src,
                                               const int* __restrict__ dst,
                                               const int* __restrict__ hmat,
                                               const int* __restrict__ coarseStart,
                                               int* __restrict__ tmp1,
                                               int E, int NC) {
    __shared__ int bcnt[MAXC];
    __shared__ int bbase[MAXC];
    int tid = threadIdx.x, blk = blockIdx.x;
    for (int i = tid; i < NC; i += 256) {
        bcnt[i] = 0;
        bbase[i] = coarseStart[i] + hmat[blk * MAXC + i];   // coalesced
    }
    __syncthreads();
    int e0 = blk * EPB, e1 = min(e0 + EPB, E);
    for (int e = e0 + tid; e < e1; e += 256) {
        int s = src[e], d = dst[e];
        int cb = d >> 8;
        int slot = bbase[cb] + atomicAdd(&bcnt[cb], 1);
        tmp1[slot] = s | ((d & 255) << 17);
    }
}

// ---- pass 2 (fused): per-bucket degree->dis/rowStart, then place into CSR ----
__global__ __launch_bounds__(DPT) void k_degplace(const int* __restrict__ tmp1,
                                                  const int* __restrict__ coarseStart,
                                                  float* __restrict__ dis,
                                                  int* __restrict__ rowStart,
                                                  int* __restrict__ esrc, int N) {
    __shared__ int hist[256];
    __shared__ int scn[256];
    __shared__ int cur[256];
    int tid = threadIdx.x;
    int cb = blockIdx.x;
    int node0 = cb << 8;
    const int r0 = coarseStart[cb], r1 = coarseStart[cb + 1];
    if (tid < 256) hist[tid] = 0;
    __syncthreads();
    for (int i = r0 + tid; i < r1; i += DPT)
        atomicAdd(&hist[((unsigned)tmp1[i]) >> 17], 1);
    __syncthreads();
    int v = 0;
    if (tid < 256) { v = hist[tid]; scn[tid] = v; }
    __syncthreads();
    for (int off = 1; off < 256; off <<= 1) {
        int a = 0;
        if (tid < 256 && tid >= off) a = scn[tid - off];
        __syncthreads();
        if (tid < 256) scn[tid] += a;
        __syncthreads();
    }
    if (tid < 256) {
        int myStart = r0 + scn[tid] - v;
        cur[tid] = myStart;
        int node = node0 + tid;
        if (node < N) {
            dis[node] = rsqrtf((float)v + 1.0f);
            rowStart[node] = myStart;
        }
    }
    __syncthreads();
    for (int i = r0 + tid; i < r1; i += DPT) {
        int pk = tmp1[i];
        int dl = ((unsigned)pk) >> 17;
        int pos = atomicAdd(&cur[dl], 1);
        esrc[pos] = (pk & 0x1FFFF) << 7;     // byte offset of bf16 row
    }
}

// ------- MFMA transform: Hbs[N,64] = bf16( (X[N,K] @ W[K,64]) * dis[row] ) -------
template <int K, typename T>
__global__ __launch_bounds__(256) void k_mmx(const T* __restrict__ X,
                                             const float* __restrict__ W,
                                             const float* __restrict__ dis,
                                             unsigned short* __restrict__ Hbs, int N) {
    constexpr int WP = K + 8;
    __shared__ unsigned short Wt[64 * WP];
    const int tid = threadIdx.x;
    for (int i = tid; i < K * 64; i += 256) {
        int k = i >> 6, n = i & 63;
        Wt[n * WP + k] = f2bf(W[i]);
    }
    __syncthreads();
    const int lane = tid & 63;
    const int m16 = lane & 15;
    const int quad = lane >> 4;
    const int rowBase = blockIdx.x * 64 + (tid >> 6) * 16;
    const int rowc = min(rowBase + m16, N - 1);

    f32x4 acc0 = {0.f, 0.f, 0.f, 0.f};
    f32x4 acc1 = acc0, acc2 = acc0, acc3 = acc0;
    const T* xrow = X + (size_t)rowc * K;
#pragma unroll
    for (int k0 = 0; k0 < K; k0 += 32) {
        bf16x8 af;
        if constexpr (sizeof(T) == 4) {
            const float* xp = (const float*)xrow + k0 + quad * 8;
            float4 xa = *(const float4*)xp;
            float4 xb = *(const float4*)(xp + 4);
            af[0] = (short)f2bf(xa.x); af[1] = (short)f2bf(xa.y);
            af[2] = (short)f2bf(xa.z); af[3] = (short)f2bf(xa.w);
            af[4] = (short)f2bf(xb.x); af[5] = (short)f2bf(xb.y);
            af[6] = (short)f2bf(xb.z); af[7] = (short)f2bf(xb.w);
        } else {
            af = *(const bf16x8*)((const unsigned short*)xrow + k0 + quad * 8);
        }
        const unsigned short* wp = &Wt[m16 * WP + k0 + quad * 8];
        bf16x8 b0 = *(const bf16x8*)(wp);
        bf16x8 b1 = *(const bf16x8*)(wp + 16 * WP);
        bf16x8 b2 = *(const bf16x8*)(wp + 32 * WP);
        bf16x8 b3 = *(const bf16x8*)(wp + 48 * WP);
        acc0 = __builtin_amdgcn_mfma_f32_16x16x32_bf16(af, b0, acc0, 0, 0, 0);
        acc1 = __builtin_amdgcn_mfma_f32_16x16x32_bf16(af, b1, acc1, 0, 0, 0);
        acc2 = __builtin_amdgcn_mfma_f32_16x16x32_bf16(af, b2, acc2, 0, 0, 0);
        acc3 = __builtin_amdgcn_mfma_f32_16x16x32_bf16(af, b3, acc3, 0, 0, 0);
    }
#pragma unroll
    for (int reg = 0; reg < 4; ++reg) {
        int r = rowBase + quad * 4 + reg;
        if (r < N) {
            float dsc = dis[r];
            unsigned short* hp = Hbs + (size_t)r * 64 + m16;
            hp[0]  = f2bf(acc0[reg] * dsc);
            hp[16] = f2bf(acc1[reg] * dsc);
            hp[32] = f2bf(acc2[reg] * dsc);
            hp[48] = f2bf(acc3[reg] * dsc);
        }
    }
}

#define BLO(d) __uint_as_float((d) << 16)
#define BHI(d) __uint_as_float((d) & 0xFFFF0000u)
#define ACC4(L, H, Q) { L.x += BLO((Q).x); L.y += BHI((Q).x);                  \
                        L.z += BLO((Q).y); L.w += BHI((Q).y);                  \
                        H.x += BLO((Q).z); H.y += BHI((Q).z);                  \
                        H.z += BLO((Q).w); H.w += BHI((Q).w); }

// octet-scheme gather body (round-7 proven): computes aL/aH for node n of this
// octet; all shfl sources stay inside the octet and bounds are octet-uniform.
#define GATHER_OCTET_BODY()                                                    \
    unsigned eoff = (Rq + c < Rq1) ? (unsigned)esrc[Rq + c] : 0u;              \
    for (int bb = Rq; bb < Rq1; bb += 8) {                                     \
        int cnt = min(8, Rq1 - bb);                                            \
        unsigned eoffN = (bb + 8 + c < Rq1) ? (unsigned)esrc[bb + 8 + c] : 0u; \
        if (cnt == 8) {                                                        \
            unsigned o0 = __shfl(eoff, ob + 0, 64);                            \
            unsigned o1 = __shfl(eoff, ob + 1, 64);                            \
            unsigned o2 = __shfl(eoff, ob + 2, 64);                            \
            unsigned o3 = __shfl(eoff, ob + 3, 64);                            \
            unsigned o4 = __shfl(eoff, ob + 4, 64);                            \
            unsigned o5 = __shfl(eoff, ob + 5, 64);                            \
            unsigned o6 = __shfl(eoff, ob + 6, 64);                            \
            unsigned o7 = __shfl(eoff, ob + 7, 64);                            \
            uint4 q0 = *(const uint4*)(hb + o0);                               \
            uint4 q1 = *(const uint4*)(hb + o1);                               \
            uint4 q2 = *(const uint4*)(hb + o2);                               \
            uint4 q3 = *(const uint4*)(hb + o3);                               \
            uint4 q4 = *(const uint4*)(hb + o4);                               \
            uint4 q5 = *(const uint4*)(hb + o5);                               \
            uint4 q6 = *(const uint4*)(hb + o6);                               \
            uint4 q7 = *(const uint4*)(hb + o7);                               \
            ACC4(aL, aH, q0) ACC4(aL, aH, q1) ACC4(aL, aH, q2) ACC4(aL, aH, q3)\
            ACC4(aL, aH, q4) ACC4(aL, aH, q5) ACC4(aL, aH, q6) ACC4(aL, aH, q7)\
        } else {                                                               \
            int j = 0;                                                         \
            if (j + 4 <= cnt) {                                                \
                unsigned o0 = __shfl(eoff, ob + j + 0, 64);                    \
                unsigned o1 = __shfl(eoff, ob + j + 1, 64);                    \
                unsigned o2 = __shfl(eoff, ob + j + 2, 64);                    \
                unsigned o3 = __shfl(eoff, ob + j + 3, 64);                    \
                uint4 q0 = *(const uint4*)(hb + o0);                           \
                uint4 q1 = *(const uint4*)(hb + o1);                           \
                uint4 q2 = *(const uint4*)(hb + o2);                           \
                uint4 q3 = *(const uint4*)(hb + o3);                           \
                ACC4(aL, aH, q0) ACC4(aL, aH, q1)                              \
                ACC4(aL, aH, q2) ACC4(aL, aH, q3)                              \
                j += 4;                                                        \
            }                                                                  \
            if (j < cnt) {                                                     \
                bool v1 = j + 1 < cnt, v2 = j + 2 < cnt;                       \
                unsigned o0 = __shfl(eoff, ob + j, 64);                        \
                unsigned o1 = __shfl(eoff, v1 ? ob + j + 1 : ob + j, 64);      \
                unsigned o2 = __shfl(eoff, v2 ? ob + j + 2 : ob + j, 64);      \
                uint4 q0 = *(const uint4*)(hb + o0);                           \
                uint4 q1 = *(const uint4*)(hb + o1);                           \
                uint4 q2 = *(const uint4*)(hb + o2);                           \
                if (!v1) { q1.x = q1.y = q1.z = q1.w = 0u; }                   \
                if (!v2) { q2.x = q2.y = q2.z = q2.w = 0u; }                   \
                ACC4(aL, aH, q0) ACC4(aL, aH, q1) ACC4(aL, aH, q2)             \
            }                                                                  \
        }                                                                      \
        eoff = eoffN;                                                          \
    }

// ------- FUSED layer-1 gather + layer-2 transform ---------------------------
// 512 threads = 8 waves; wave wv gathers 8 nodes (octet scheme) and writes the
// relu'd bf16 rows to LDS (no Hb1 global round-trip); then waves 0-3 run the
// K=64 MFMA transform reading A-fragments from LDS, writing Hout (*dis).
__global__ __launch_bounds__(512) void k_gmx(const unsigned short* __restrict__ Hbs,
                                             const int* __restrict__ esrc,
                                             const int* __restrict__ rowStart,
                                             const float* __restrict__ dis,
                                             const float* __restrict__ b,   // b1
                                             const float* __restrict__ W,   // W2
                                             unsigned short* __restrict__ Hout,
                                             int N) {
    __shared__ unsigned short Hrow[64 * 72];   // 64 gathered rows, +8 pad
    __shared__ unsigned short Wt[64 * 72];     // W2^T staged [n][k], +8 pad
    const int tid = threadIdx.x;
    for (int i = tid; i < 64 * 64; i += 512) { // stage W2 (f32 [k][n]) as bf16
        int k = i >> 6, n = i & 63;
        Wt[n * 72 + k] = f2bf(W[i]);
    }
    const int lane = tid & 63;
    const int c = lane & 7;            // 16B chunk of the 128B row
    const int oct = lane >> 3;         // octet index == node slot
    const int ob = oct << 3;           // octet's first lane (shfl base)
    const int wv = tid >> 6;           // wave 0..7
    const int g0 = blockIdx.x * 64 + wv * 8;
    const char* hb = (const char*)Hbs + c * 16;

    int rb = rowStart[min(g0 + lane, N)];
    int Rq  = __shfl(rb, oct, 64);
    int Rq1 = __shfl(rb, oct + 1, 64);
    int n = g0 + oct;
    int nc = min(n, N - 1);            // n>=N octets: Rq==Rq1==E (no edges)

    float4 aL, aH;
    {
        uint4 sd = *(const uint4*)(hb + ((size_t)nc << 7));   // self-loop seed
        aL.x = BLO(sd.x); aL.y = BHI(sd.x); aL.z = BLO(sd.y); aL.w = BHI(sd.y);
        aH.x = BLO(sd.z); aH.y = BHI(sd.z); aH.z = BLO(sd.w); aH.w = BHI(sd.w);
    }
    GATHER_OCTET_BODY()

    {   // epilogue: relu row -> LDS (rows for n>=N are garbage, outputs guarded)
        float ds = dis[nc];
        float4 bL = ((const float4*)b)[2 * c];
        float4 bH = ((const float4*)b)[2 * c + 1];
        uint4 pv;
        pv.x = (unsigned)f2bf(fmaxf(aL.x * ds + bL.x, 0.f))
             | ((unsigned)f2bf(fmaxf(aL.y * ds + bL.y, 0.f)) << 16);
        pv.y = (unsigned)f2bf(fmaxf(aL.z * ds + bL.z, 0.f))
             | ((unsigned)f2bf(fmaxf(aL.w * ds + bL.w, 0.f)) << 16);
        pv.z = (unsigned)f2bf(fmaxf(aH.x * ds + bH.x, 0.f))
             | ((unsigned)f2bf(fmaxf(aH.y * ds + bH.y, 0.f)) << 16);
        pv.w = (unsigned)f2bf(fmaxf(aH.z * ds + bH.z, 0.f))
             | ((unsigned)f2bf(fmaxf(aH.w * ds + bH.w, 0.f)) << 16);
        ((uint4*)&Hrow[(wv * 8 + oct) * 72])[c] = pv;   // 144B row stride, 16B aligned
    }
    __syncthreads();

    // ---- layer-2 transform: waves 0-3, 16 rows each, K=64 from LDS ----
    if (wv < 4) {
        const int m16 = lane & 15;
        const int quad = lane >> 4;
        const int rowBase = blockIdx.x * 64 + wv * 16;
        f32x4 acc0 = {0.f, 0.f, 0.f, 0.f};
        f32x4 acc1 = acc0, acc2 = acc0, acc3 = acc0;
#pragma unroll
        for (int k0 = 0; k0 < 64; k0 += 32) {
            bf16x8 af = *(const bf16x8*)&Hrow[(wv * 16 + m16) * 72 + k0 + quad * 8];
            const unsigned short* wp = &Wt[m16 * 72 + k0 + quad * 8];
            bf16x8 b0 = *(const bf16x8*)(wp);
            bf16x8 b1 = *(const bf16x8*)(wp + 16 * 72);
            bf16x8 b2 = *(const bf16x8*)(wp + 32 * 72);
            bf16x8 b3 = *(const bf16x8*)(wp + 48 * 72);
            acc0 = __builtin_amdgcn_mfma_f32_16x16x32_bf16(af, b0, acc0, 0, 0, 0);
            acc1 = __builtin_amdgcn_mfma_f32_16x16x32_bf16(af, b1, acc1, 0, 0, 0);
            acc2 = __builtin_amdgcn_mfma_f32_16x16x32_bf16(af, b2, acc2, 0, 0, 0);
            acc3 = __builtin_amdgcn_mfma_f32_16x16x32_bf16(af, b3, acc3, 0, 0, 0);
        }
#pragma unroll
        for (int reg = 0; reg < 4; ++reg) {
            int r = rowBase + quad * 4 + reg;
            if (r < N) {
                float dsc = dis[r];
                unsigned short* hp = Hout + (size_t)r * 64 + m16;
                hp[0]  = f2bf(acc0[reg] * dsc);
                hp[16] = f2bf(acc1[reg] * dsc);
                hp[32] = f2bf(acc2[reg] * dsc);
                hp[48] = f2bf(acc3[reg] * dsc);
            }
        }
    }
}

// ------- layer-2 gather fused with W3 dot (round-7 proven octet scheme) ------
__global__ __launch_bounds__(256) void k_gatherW3(const unsigned short* __restrict__ Hbs,
                                                  const int* __restrict__ esrc,
                                                  const int* __restrict__ rowStart,
                                                  const float* __restrict__ dis,
                                                  const float* __restrict__ b,
                                                  const float* __restrict__ W3,
                                                  const float* __restrict__ b3,
                                                  float* __restrict__ colS,
                                                  float* __restrict__ outF,
                                                  int N) {
    int lane = threadIdx.x & 63;
    int c = lane & 7;
    int oct = lane >> 3;
    int ob = oct << 3;
    int wave = (blockIdx.x * 256 + threadIdx.x) >> 6;
    int g0 = wave * 8;
    if (g0 >= N) return;
    const char* hb = (const char*)Hbs + c * 16;

    int rb = rowStart[min(g0 + lane, N)];
    int Rq  = __shfl(rb, oct, 64);
    int Rq1 = __shfl(rb, oct + 1, 64);
    int n = g0 + oct;
    int nc = min(n, N - 1);

    float4 aL, aH;
    {
        uint4 sd = *(const uint4*)(hb + ((size_t)nc << 7));
        aL.x = BLO(sd.x); aL.y = BHI(sd.x); aL.z = BLO(sd.y); aL.w = BHI(sd.y);
        aH.x = BLO(sd.z); aH.y = BHI(sd.z); aH.z = BLO(sd.w); aH.w = BHI(sd.w);
    }
    GATHER_OCTET_BODY()

    float ds = dis[nc];
    float4 bL = ((const float4*)b)[2 * c];
    float4 bH = ((const float4*)b)[2 * c + 1];
    float4 vL, vH;
    vL.x = fmaxf(aL.x * ds + bL.x, 0.f);
    vL.y = fmaxf(aL.y * ds + bL.y, 0.f);
    vL.z = fmaxf(aL.z * ds + bL.z, 0.f);
    vL.w = fmaxf(aL.w * ds + bL.w, 0.f);
    vH.x = fmaxf(aH.x * ds + bH.x, 0.f);
    vH.y = fmaxf(aH.y * ds + bH.y, 0.f);
    vH.z = fmaxf(aH.z * ds + bH.z, 0.f);
    vH.w = fmaxf(aH.w * ds + bH.w, 0.f);

    float4 wL = ((const float4*)W3)[2 * c];
    float4 wH = ((const float4*)W3)[2 * c + 1];
    float t = vL.x * wL.x + vL.y * wL.y + vL.z * wL.z + vL.w * wL.w
            + vH.x * wH.x + vH.y * wH.y + vH.z * wH.z + vH.w * wH.w;
    t += __shfl_xor(t, 1, 64);
    t += __shfl_xor(t, 2, 64);
    t += __shfl_xor(t, 4, 64);
    if (c == 0 && n < N) {
        colS[n] = t * ds;
        outF[n] = t * ds * ds + b3[0];
    }
}

// layer-3 aggregation: stage block's colS values in LDS, per-node sum from LDS
__global__ __launch_bounds__(256) void k_gather1(const float* __restrict__ colS,
                                                 const int* __restrict__ esrc,
                                                 const int* __restrict__ rowStart,
                                                 const float* __restrict__ dis,
                                                 float* __restrict__ out, int N) {
    __shared__ float ls[G1CAP];
    int tid = threadIdx.x;
    int n0 = blockIdx.x * 256;
    int nEnd = min(n0 + 256, N);
    int r0 = rowStart[n0];
    int r1 = rowStart[nEnd];
    int cnt = r1 - r0;
    if (cnt <= G1CAP) {
        for (int i = tid; i < cnt; i += 256)
            ls[i] = colS[((unsigned)esrc[r0 + i]) >> 7];
        __syncthreads();
        int n = n0 + tid;
        if (n < N) {
            int a = rowStart[n] - r0, bnd = rowStart[n + 1] - r0;
            float acc = 0.0f;
            for (int e = a; e < bnd; ++e) acc += ls[e];
            out[n] += acc * dis[n];
        }
    } else {   // statistically unreachable fallback
        int n = n0 + tid;
        if (n < N) {
            int a = rowStart[n], bnd = rowStart[n + 1];
            float acc = 0.0f;
            for (int e = a; e < bnd; ++e) acc += colS[((unsigned)esrc[e]) >> 7];
            out[n] += acc * dis[n];
        }
    }
}

extern "C" void kernel_launch(void* const* d_in, const int* in_sizes, int n_in,
                              void* d_out, int out_size, void* d_ws, size_t ws_size,
                              hipStream_t stream) {
    const float* x  = (const float*)d_in[0];
    const int*   ei = (const int*)d_in[1];
    const float* W1 = (const float*)d_in[2];
    const float* b1 = (const float*)d_in[3];
    const float* W2 = (const float*)d_in[4];
    const float* b2 = (const float*)d_in[5];
    const float* W3 = (const float*)d_in[6];
    const float* b3 = (const float*)d_in[7];
    float* out = (float*)d_out;

    const int N = in_sizes[0] / IN_DIM;     // 100000
    const int E = in_sizes[1] / 2;          // 1600000
    const int* src = ei;
    const int* dst = ei + E;
    const int NC = (N + 255) >> 8;          // 391 coarse buckets
    const int NBLK = (E + EPB - 1) / EPB;   // 391 partition blocks

    // ---- workspace layout ----
    char* w = (char*)d_ws;
    auto alloc = [&](size_t bytes) {
        char* p = w;
        w += (bytes + 1023) & ~(size_t)1023;
        return p;
    };
    float*          dis        = (float*)alloc((size_t)N * 4);
    unsigned short* Hbs        = (unsigned short*)alloc((size_t)N * 64 * 2);
    unsigned short* Hb1        = (unsigned short*)alloc((size_t)N * 64 * 2);
    float*          colS       = (float*)alloc((size_t)N * 4);
    int*            rowStart   = (int*)alloc((size_t)(N + 1) * 4);
    int*            bktTotal   = (int*)alloc((size_t)MAXC * 4);
    int*            coarseStart= (int*)alloc((size_t)(MAXC + 1) * 4);
    int*            hmat       = (int*)alloc((size_t)MAXB * MAXC * 4);
    int*            esrc       = (int*)alloc((size_t)E * 4 + 1024);
    int*            tmp1       = (int*)alloc((size_t)E * 4);
    int*            ctr        = (int*)alloc(64);

    const int NB_N   = (N + 255) / 256;
    const int NB_MX  = (N + 63) / 64;                    // MFMA transform blocks
    const int NB_G8  = (((N + 7) / 8) * 64 + 255) / 256; // 8 nodes per wave
    const int NB_GMX = (N + 63) / 64;                    // 64 nodes per block

    // ---- deterministic partition (4 kernels; cscan folded into bktscan) ----
    k_hist2<<<NBLK, 256, 0, stream>>>(dst, hmat, ctr, E, NC);
    k_bktscan<<<NC, 512, 0, stream>>>(hmat, bktTotal, ctr, coarseStart, rowStart,
                                      NBLK, NC, N, E);
    k_part1<<<NBLK, 256, 0, stream>>>(src, dst, hmat, coarseStart, tmp1, E, NC);
    k_degplace<<<NC, DPT, 0, stream>>>(tmp1, coarseStart, dis, rowStart, esrc, N);

    // ---- layer 1 transform ----
    k_mmx<IN_DIM, float><<<NB_MX, 256, 0, stream>>>(x, W1, dis, Hbs, N);

    // ---- fused: layer-1 gather + layer-2 transform (Hbs -> Hb1, via LDS) ----
    k_gmx<<<NB_GMX, 512, 0, stream>>>(Hbs, esrc, rowStart, dis, b1, W2, Hb1, N);

    // ---- layer-2 gather fused with W3 dot ----
    k_gatherW3<<<NB_G8, 256, 0, stream>>>(Hb1, esrc, rowStart, dis, b2,
                                          W3, b3, colS, out, N);

    // ---- layer 3 aggregation ----
    k_gather1<<<NB_N, 256, 0, stream>>>(colS, esrc, rowStart, dis, out, N);
}

// Round 10
// 227.834 us; speedup vs baseline: 1.9586x; 1.0088x over previous
//
#include <hip/hip_runtime.h>

#define IN_DIM 128
#define HID 64
#define MAXC 400            // >= ceil(N/256); N=100000 -> 391 coarse buckets
#define MAXB 512            // >= NBLK = ceil(E/EPB) = 391
#define EPB 4096
#define DPT 512             // degplace threads per block
#define G1CAP 6144          // LDS floats for k_gather1 staging (E[block]=4096, +32 sigma)

// ---- bf16 helpers (RNE) ----
static __device__ __forceinline__ unsigned short f2bf(float f) {
    unsigned u = __float_as_uint(f);
    u += 0x7FFF + ((u >> 16) & 1);
    return (unsigned short)(u >> 16);
}

typedef short bf16x8 __attribute__((ext_vector_type(8)));
typedef float f32x4 __attribute__((ext_vector_type(4)));

// ---- pass 0: per-block bucket histogram -> hmat[blk][cb]; blk0 zeroes ctr ----
__global__ __launch_bounds__(256) void k_hist2(const int* __restrict__ dst,
                                               int* __restrict__ hmat,
                                               int* __restrict__ ctr, int E, int NC) {
    __shared__ int h[MAXC];
    int tid = threadIdx.x, blk = blockIdx.x;
    if (blk == 0 && tid == 0) ctr[0] = 0;
    for (int i = tid; i < NC; i += 256) h[i] = 0;
    __syncthreads();
    int e0 = blk * EPB, e1 = min(e0 + EPB, E);
    for (int e = e0 + tid; e < e1; e += 256) atomicAdd(&h[dst[e] >> 8], 1);
    __syncthreads();
    for (int i = tid; i < NC; i += 256) hmat[blk * MAXC + i] = h[i];
}

// ---- per-bucket exclusive scan across blocks + (last block) bucket-total scan ----
// Cross-block comms via device-scope atomics only (coherence point), per G16.
__global__ __launch_bounds__(512) void k_bktscan(int* __restrict__ hmat,
                                                 int* __restrict__ bktTotal,
                                                 int* __restrict__ ctr,
                                                 int* __restrict__ coarseStart,
                                                 int* __restrict__ rowStart,
                                                 int NBLK, int NC, int N, int E) {
    __shared__ int tmp[512];
    __shared__ int lastFlag;
    int cb = blockIdx.x;
    int t = threadIdx.x;
    int v = (t < NBLK) ? hmat[t * MAXC + cb] : 0;
    tmp[t] = v;
    __syncthreads();
    for (int off = 1; off < 512; off <<= 1) {
        int a = (t >= off) ? tmp[t - off] : 0;
        __syncthreads();
        tmp[t] += a;
        __syncthreads();
    }
    if (t < NBLK) hmat[t * MAXC + cb] = tmp[t] - v;   // exclusive prefix within bucket
    if (t == 511) atomicExch(&bktTotal[cb], tmp[511]); // coherence-point publish
    __syncthreads();                                   // drains the atomic (vmcnt)
    if (t == 0) lastFlag = (atomicAdd(ctr, 1) == (int)gridDim.x - 1);
    __syncthreads();
    if (!lastFlag) return;
    // last arriving block: scan bucket totals -> coarseStart
    int v2 = (t < NC) ? atomicAdd(&bktTotal[t], 0) : 0;  // coherence-point read
    tmp[t] = v2;
    __syncthreads();
    for (int off = 1; off < 512; off <<= 1) {
        int a = (t >= off) ? tmp[t - off] : 0;
        __syncthreads();
        tmp[t] += a;
        __syncthreads();
    }
    int excl = tmp[t] - v2;
    if (t < NC) coarseStart[t] = excl;
    if (t == NC - 1) coarseStart[NC] = excl + v2;   // == E
    if (t == 0) rowStart[N] = E;
}

// ---- pass 1: deterministic placement into dense coarse-sorted array ----
__global__ __launch_bounds__(256) void k_part1(const int* __restrict__ src,
                                               const int* __restrict__ dst,
                                               const int* __restrict__ hmat,
                                               const int* __restrict__ coarseStart,
                                               int* __restrict__ tmp1,
                                               int E, int NC) {
    __shared__ int bcnt[MAXC];
    __shared__ int bbase[MAXC];
    int tid = threadIdx.x, blk = blockIdx.x;
    for (int i = tid; i < NC; i += 256) {
        bcnt[i] = 0;
        bbase[i] = coarseStart[i] + hmat[blk * MAXC + i];   // coalesced
    }
    __syncthreads();
    int e0 = blk * EPB, e1 = min(e0 + EPB, E);
    for (int e = e0 + tid; e < e1; e += 256) {
        int s = src[e], d = dst[e];
        int cb = d >> 8;
        int slot = bbase[cb] + atomicAdd(&bcnt[cb], 1);
        tmp1[slot] = s | ((d & 255) << 17);
    }
}

// ---- pass 2 (fused): per-bucket degree->dis/rowStart, then place into CSR ----
__global__ __launch_bounds__(DPT) void k_degplace(const int* __restrict__ tmp1,
                                                  const int* __restrict__ coarseStart,
                                                  float* __restrict__ dis,
                                                  int* __restrict__ rowStart,
                                                  int* __restrict__ esrc, int N) {
    __shared__ int hist[256];
    __shared__ int scn[256];
    __shared__ int cur[256];
    int tid = threadIdx.x;
    int cb = blockIdx.x;
    int node0 = cb << 8;
    const int r0 = coarseStart[cb], r1 = coarseStart[cb + 1];
    if (tid < 256) hist[tid] = 0;
    __syncthreads();
    for (int i = r0 + tid; i < r1; i += DPT)
        atomicAdd(&hist[((unsigned)tmp1[i]) >> 17], 1);
    __syncthreads();
    int v = 0;
    if (tid < 256) { v = hist[tid]; scn[tid] = v; }
    __syncthreads();
    for (int off = 1; off < 256; off <<= 1) {
        int a = 0;
        if (tid < 256 && tid >= off) a = scn[tid - off];
        __syncthreads();
        if (tid < 256) scn[tid] += a;
        __syncthreads();
    }
    if (tid < 256) {
        int myStart = r0 + scn[tid] - v;
        cur[tid] = myStart;
        int node = node0 + tid;
        if (node < N) {
            dis[node] = rsqrtf((float)v + 1.0f);
            rowStart[node] = myStart;
        }
    }
    __syncthreads();
    for (int i = r0 + tid; i < r1; i += DPT) {
        int pk = tmp1[i];
        int dl = ((unsigned)pk) >> 17;
        int pos = atomicAdd(&cur[dl], 1);
        esrc[pos] = (pk & 0x1FFFF) << 7;     // byte offset of bf16 row
    }
}

// ------- MFMA transform: Hbs[N,64] = bf16( (X[N,K] @ W[K,64]) * dis[row] ) -------
template <int K, typename T>
__global__ __launch_bounds__(256) void k_mmx(const T* __restrict__ X,
                                             const float* __restrict__ W,
                                             const float* __restrict__ dis,
                                             unsigned short* __restrict__ Hbs, int N) {
    constexpr int WP = K + 8;
    __shared__ unsigned short Wt[64 * WP];
    const int tid = threadIdx.x;
    for (int i = tid; i < K * 64; i += 256) {
        int k = i >> 6, n = i & 63;
        Wt[n * WP + k] = f2bf(W[i]);
    }
    __syncthreads();
    const int lane = tid & 63;
    const int m16 = lane & 15;
    const int quad = lane >> 4;
    const int rowBase = blockIdx.x * 64 + (tid >> 6) * 16;
    const int rowc = min(rowBase + m16, N - 1);

    f32x4 acc0 = {0.f, 0.f, 0.f, 0.f};
    f32x4 acc1 = acc0, acc2 = acc0, acc3 = acc0;
    const T* xrow = X + (size_t)rowc * K;
#pragma unroll
    for (int k0 = 0; k0 < K; k0 += 32) {
        bf16x8 af;
        if constexpr (sizeof(T) == 4) {
            const float* xp = (const float*)xrow + k0 + quad * 8;
            float4 xa = *(const float4*)xp;
            float4 xb = *(const float4*)(xp + 4);
            af[0] = (short)f2bf(xa.x); af[1] = (short)f2bf(xa.y);
            af[2] = (short)f2bf(xa.z); af[3] = (short)f2bf(xa.w);
            af[4] = (short)f2bf(xb.x); af[5] = (short)f2bf(xb.y);
            af[6] = (short)f2bf(xb.z); af[7] = (short)f2bf(xb.w);
        } else {
            af = *(const bf16x8*)((const unsigned short*)xrow + k0 + quad * 8);
        }
        const unsigned short* wp = &Wt[m16 * WP + k0 + quad * 8];
        bf16x8 b0 = *(const bf16x8*)(wp);
        bf16x8 b1 = *(const bf16x8*)(wp + 16 * WP);
        bf16x8 b2 = *(const bf16x8*)(wp + 32 * WP);
        bf16x8 b3 = *(const bf16x8*)(wp + 48 * WP);
        acc0 = __builtin_amdgcn_mfma_f32_16x16x32_bf16(af, b0, acc0, 0, 0, 0);
        acc1 = __builtin_amdgcn_mfma_f32_16x16x32_bf16(af, b1, acc1, 0, 0, 0);
        acc2 = __builtin_amdgcn_mfma_f32_16x16x32_bf16(af, b2, acc2, 0, 0, 0);
        acc3 = __builtin_amdgcn_mfma_f32_16x16x32_bf16(af, b3, acc3, 0, 0, 0);
    }
#pragma unroll
    for (int reg = 0; reg < 4; ++reg) {
        int r = rowBase + quad * 4 + reg;
        if (r < N) {
            float dsc = dis[r];
            unsigned short* hp = Hbs + (size_t)r * 64 + m16;
            hp[0]  = f2bf(acc0[reg] * dsc);
            hp[16] = f2bf(acc1[reg] * dsc);
            hp[32] = f2bf(acc2[reg] * dsc);
            hp[48] = f2bf(acc3[reg] * dsc);
        }
    }
}

#define BLO(d) __uint_as_float((d) << 16)
#define BHI(d) __uint_as_float((d) & 0xFFFF0000u)
#define ACC4(L, H, Q) { L.x += BLO((Q).x); L.y += BHI((Q).x);                  \
                        L.z += BLO((Q).y); L.w += BHI((Q).y);                  \
                        H.x += BLO((Q).z); H.y += BHI((Q).z);                  \
                        H.z += BLO((Q).w); H.w += BHI((Q).w); }

// octet-scheme gather body (round-7 proven): computes aL/aH for node n of this
// octet; all shfl sources stay inside the octet and bounds are octet-uniform.
#define GATHER_OCTET_BODY()                                                    \
    unsigned eoff = (Rq + c < Rq1) ? (unsigned)esrc[Rq + c] : 0u;              \
    for (int bb = Rq; bb < Rq1; bb += 8) {                                     \
        int cnt = min(8, Rq1 - bb);                                            \
        unsigned eoffN = (bb + 8 + c < Rq1) ? (unsigned)esrc[bb + 8 + c] : 0u; \
        if (cnt == 8) {                                                        \
            unsigned o0 = __shfl(eoff, ob + 0, 64);                            \
            unsigned o1 = __shfl(eoff, ob + 1, 64);                            \
            unsigned o2 = __shfl(eoff, ob + 2, 64);                            \
            unsigned o3 = __shfl(eoff, ob + 3, 64);                            \
            unsigned o4 = __shfl(eoff, ob + 4, 64);                            \
            unsigned o5 = __shfl(eoff, ob + 5, 64);                            \
            unsigned o6 = __shfl(eoff, ob + 6, 64);                            \
            unsigned o7 = __shfl(eoff, ob + 7, 64);                            \
            uint4 q0 = *(const uint4*)(hb + o0);                               \
            uint4 q1 = *(const uint4*)(hb + o1);                               \
            uint4 q2 = *(const uint4*)(hb + o2);                               \
            uint4 q3 = *(const uint4*)(hb + o3);                               \
            uint4 q4 = *(const uint4*)(hb + o4);                               \
            uint4 q5 = *(const uint4*)(hb + o5);                               \
            uint4 q6 = *(const uint4*)(hb + o6);                               \
            uint4 q7 = *(const uint4*)(hb + o7);                               \
            ACC4(aL, aH, q0) ACC4(aL, aH, q1) ACC4(aL, aH, q2) ACC4(aL, aH, q3)\
            ACC4(aL, aH, q4) ACC4(aL, aH, q5) ACC4(aL, aH, q6) ACC4(aL, aH, q7)\
        } else {                                                               \
            int j = 0;                                                         \
            if (j + 4 <= cnt) {                                                \
                unsigned o0 = __shfl(eoff, ob + j + 0, 64);                    \
                unsigned o1 = __shfl(eoff, ob + j + 1, 64);                    \
                unsigned o2 = __shfl(eoff, ob + j + 2, 64);                    \
                unsigned o3 = __shfl(eoff, ob + j + 3, 64);                    \
                uint4 q0 = *(const uint4*)(hb + o0);                           \
                uint4 q1 = *(const uint4*)(hb + o1);                           \
                uint4 q2 = *(const uint4*)(hb + o2);                           \
                uint4 q3 = *(const uint4*)(hb + o3);                           \
                ACC4(aL, aH, q0) ACC4(aL, aH, q1)                              \
                ACC4(aL, aH, q2) ACC4(aL, aH, q3)                              \
                j += 4;                                                        \
            }                                                                  \
            if (j < cnt) {                                                     \
                bool v1 = j + 1 < cnt, v2 = j + 2 < cnt;                       \
                unsigned o0 = __shfl(eoff, ob + j, 64);                        \
                unsigned o1 = __shfl(eoff, v1 ? ob + j + 1 : ob + j, 64);      \
                unsigned o2 = __shfl(eoff, v2 ? ob + j + 2 : ob + j, 64);      \
                uint4 q0 = *(const uint4*)(hb + o0);                           \
                uint4 q1 = *(const uint4*)(hb + o1);                           \
                uint4 q2 = *(const uint4*)(hb + o2);                           \
                if (!v1) { q1.x = q1.y = q1.z = q1.w = 0u; }                   \
                if (!v2) { q2.x = q2.y = q2.z = q2.w = 0u; }                   \
                ACC4(aL, aH, q0) ACC4(aL, aH, q1) ACC4(aL, aH, q2)             \
            }                                                                  \
        }                                                                      \
        eoff = eoffN;                                                          \
    }

// ------- FUSED layer-1 gather + layer-2 transform (256-thread rebalance) -----
// 256 threads = 4 waves; wave wv gathers 8 nodes (octet scheme) into LDS; then
// waves 0-1 run the K=64 MFMA transform over the 32 rows. Smaller barrier set
// (max over 4 waves, not 8) cuts straggler time; 8 blocks/CU schedulable.
__global__ __launch_bounds__(256) void k_gmx(const unsigned short* __restrict__ Hbs,
                                             const int* __restrict__ esrc,
                                             const int* __restrict__ rowStart,
                                             const float* __restrict__ dis,
                                             const float* __restrict__ b,   // b1
                                             const float* __restrict__ W,   // W2
                                             unsigned short* __restrict__ Hout,
                                             int N) {
    __shared__ unsigned short Hrow[32 * 72];   // 32 gathered rows, +8 pad
    __shared__ unsigned short Wt[64 * 72];     // W2^T staged [n][k], +8 pad
    const int tid = threadIdx.x;
    for (int i = tid; i < 64 * 64; i += 256) { // stage W2 (f32 [k][n]) as bf16
        int k = i >> 6, n = i & 63;
        Wt[n * 72 + k] = f2bf(W[i]);
    }
    const int lane = tid & 63;
    const int c = lane & 7;            // 16B chunk of the 128B row
    const int oct = lane >> 3;         // octet index == node slot
    const int ob = oct << 3;           // octet's first lane (shfl base)
    const int wv = tid >> 6;           // wave 0..3
    const int g0 = blockIdx.x * 32 + wv * 8;
    const char* hb = (const char*)Hbs + c * 16;

    int rb = rowStart[min(g0 + lane, N)];
    int Rq  = __shfl(rb, oct, 64);
    int Rq1 = __shfl(rb, oct + 1, 64);
    int n = g0 + oct;
    int nc = min(n, N - 1);            // n>=N octets: Rq==Rq1==E (no edges)

    float4 aL, aH;
    {
        uint4 sd = *(const uint4*)(hb + ((size_t)nc << 7));   // self-loop seed
        aL.x = BLO(sd.x); aL.y = BHI(sd.x); aL.z = BLO(sd.y); aL.w = BHI(sd.y);
        aH.x = BLO(sd.z); aH.y = BHI(sd.z); aH.z = BLO(sd.w); aH.w = BHI(sd.w);
    }
    GATHER_OCTET_BODY()

    {   // epilogue: relu row -> LDS (rows for n>=N are garbage, outputs guarded)
        float ds = dis[nc];
        float4 bL = ((const float4*)b)[2 * c];
        float4 bH = ((const float4*)b)[2 * c + 1];
        uint4 pv;
        pv.x = (unsigned)f2bf(fmaxf(aL.x * ds + bL.x, 0.f))
             | ((unsigned)f2bf(fmaxf(aL.y * ds + bL.y, 0.f)) << 16);
        pv.y = (unsigned)f2bf(fmaxf(aL.z * ds + bL.z, 0.f))
             | ((unsigned)f2bf(fmaxf(aL.w * ds + bL.w, 0.f)) << 16);
        pv.z = (unsigned)f2bf(fmaxf(aH.x * ds + bH.x, 0.f))
             | ((unsigned)f2bf(fmaxf(aH.y * ds + bH.y, 0.f)) << 16);
        pv.w = (unsigned)f2bf(fmaxf(aH.z * ds + bH.z, 0.f))
             | ((unsigned)f2bf(fmaxf(aH.w * ds + bH.w, 0.f)) << 16);
        ((uint4*)&Hrow[(wv * 8 + oct) * 72])[c] = pv;   // 144B row stride, 16B aligned
    }
    __syncthreads();

    // ---- layer-2 transform: waves 0-1, 16 rows each, K=64 from LDS ----
    if (wv < 2) {
        const int m16 = lane & 15;
        const int quad = lane >> 4;
        const int rowBase = blockIdx.x * 32 + wv * 16;
        f32x4 acc0 = {0.f, 0.f, 0.f, 0.f};
        f32x4 acc1 = acc0, acc2 = acc0, acc3 = acc0;
#pragma unroll
        for (int k0 = 0; k0 < 64; k0 += 32) {
            bf16x8 af = *(const bf16x8*)&Hrow[(wv * 16 + m16) * 72 + k0 + quad * 8];
            const unsigned short* wp = &Wt[m16 * 72 + k0 + quad * 8];
            bf16x8 b0 = *(const bf16x8*)(wp);
            bf16x8 b1 = *(const bf16x8*)(wp + 16 * 72);
            bf16x8 b2 = *(const bf16x8*)(wp + 32 * 72);
            bf16x8 b3 = *(const bf16x8*)(wp + 48 * 72);
            acc0 = __builtin_amdgcn_mfma_f32_16x16x32_bf16(af, b0, acc0, 0, 0, 0);
            acc1 = __builtin_amdgcn_mfma_f32_16x16x32_bf16(af, b1, acc1, 0, 0, 0);
            acc2 = __builtin_amdgcn_mfma_f32_16x16x32_bf16(af, b2, acc2, 0, 0, 0);
            acc3 = __builtin_amdgcn_mfma_f32_16x16x32_bf16(af, b3, acc3, 0, 0, 0);
        }
#pragma unroll
        for (int reg = 0; reg < 4; ++reg) {
            int r = rowBase + quad * 4 + reg;
            if (r < N) {
                float dsc = dis[r];
                unsigned short* hp = Hout + (size_t)r * 64 + m16;
                hp[0]  = f2bf(acc0[reg] * dsc);
                hp[16] = f2bf(acc1[reg] * dsc);
                hp[32] = f2bf(acc2[reg] * dsc);
                hp[48] = f2bf(acc3[reg] * dsc);
            }
        }
    }
}

// ------- layer-2 gather fused with W3 dot (round-7 proven octet scheme) ------
__global__ __launch_bounds__(256) void k_gatherW3(const unsigned short* __restrict__ Hbs,
                                                  const int* __restrict__ esrc,
                                                  const int* __restrict__ rowStart,
                                                  const float* __restrict__ dis,
                                                  const float* __restrict__ b,
                                                  const float* __restrict__ W3,
                                                  const float* __restrict__ b3,
                                                  float* __restrict__ colS,
                                                  float* __restrict__ outF,
                                                  int N) {
    int lane = threadIdx.x & 63;
    int c = lane & 7;
    int oct = lane >> 3;
    int ob = oct << 3;
    int wave = (blockIdx.x * 256 + threadIdx.x) >> 6;
    int g0 = wave * 8;
    if (g0 >= N) return;
    const char* hb = (const char*)Hbs + c * 16;

    int rb = rowStart[min(g0 + lane, N)];
    int Rq  = __shfl(rb, oct, 64);
    int Rq1 = __shfl(rb, oct + 1, 64);
    int n = g0 + oct;
    int nc = min(n, N - 1);

    float4 aL, aH;
    {
        uint4 sd = *(const uint4*)(hb + ((size_t)nc << 7));
        aL.x = BLO(sd.x); aL.y = BHI(sd.x); aL.z = BLO(sd.y); aL.w = BHI(sd.y);
        aH.x = BLO(sd.z); aH.y = BHI(sd.z); aH.z = BLO(sd.w); aH.w = BHI(sd.w);
    }
    GATHER_OCTET_BODY()

    float ds = dis[nc];
    float4 bL = ((const float4*)b)[2 * c];
    float4 bH = ((const float4*)b)[2 * c + 1];
    float4 vL, vH;
    vL.x = fmaxf(aL.x * ds + bL.x, 0.f);
    vL.y = fmaxf(aL.y * ds + bL.y, 0.f);
    vL.z = fmaxf(aL.z * ds + bL.z, 0.f);
    vL.w = fmaxf(aL.w * ds + bL.w, 0.f);
    vH.x = fmaxf(aH.x * ds + bH.x, 0.f);
    vH.y = fmaxf(aH.y * ds + bH.y, 0.f);
    vH.z = fmaxf(aH.z * ds + bH.z, 0.f);
    vH.w = fmaxf(aH.w * ds + bH.w, 0.f);

    float4 wL = ((const float4*)W3)[2 * c];
    float4 wH = ((const float4*)W3)[2 * c + 1];
    float t = vL.x * wL.x + vL.y * wL.y + vL.z * wL.z + vL.w * wL.w
            + vH.x * wH.x + vH.y * wH.y + vH.z * wH.z + vH.w * wH.w;
    t += __shfl_xor(t, 1, 64);
    t += __shfl_xor(t, 2, 64);
    t += __shfl_xor(t, 4, 64);
    if (c == 0 && n < N) {
        colS[n] = t * ds;
        outF[n] = t * ds * ds + b3[0];
    }
}

// layer-3 aggregation: stage block's colS values in LDS, per-node sum from LDS
__global__ __launch_bounds__(256) void k_gather1(const float* __restrict__ colS,
                                                 const int* __restrict__ esrc,
                                                 const int* __restrict__ rowStart,
                                                 const float* __restrict__ dis,
                                                 float* __restrict__ out, int N) {
    __shared__ float ls[G1CAP];
    int tid = threadIdx.x;
    int n0 = blockIdx.x * 256;
    int nEnd = min(n0 + 256, N);
    int r0 = rowStart[n0];
    int r1 = rowStart[nEnd];
    int cnt = r1 - r0;
    if (cnt <= G1CAP) {
        for (int i = tid; i < cnt; i += 256)
            ls[i] = colS[((unsigned)esrc[r0 + i]) >> 7];
        __syncthreads();
        int n = n0 + tid;
        if (n < N) {
            int a = rowStart[n] - r0, bnd = rowStart[n + 1] - r0;
            float acc = 0.0f;
            for (int e = a; e < bnd; ++e) acc += ls[e];
            out[n] += acc * dis[n];
        }
    } else {   // statistically unreachable fallback
        int n = n0 + tid;
        if (n < N) {
            int a = rowStart[n], bnd = rowStart[n + 1];
            float acc = 0.0f;
            for (int e = a; e < bnd; ++e) acc += colS[((unsigned)esrc[e]) >> 7];
            out[n] += acc * dis[n];
        }
    }
}

extern "C" void kernel_launch(void* const* d_in, const int* in_sizes, int n_in,
                              void* d_out, int out_size, void* d_ws, size_t ws_size,
                              hipStream_t stream) {
    const float* x  = (const float*)d_in[0];
    const int*   ei = (const int*)d_in[1];
    const float* W1 = (const float*)d_in[2];
    const float* b1 = (const float*)d_in[3];
    const float* W2 = (const float*)d_in[4];
    const float* b2 = (const float*)d_in[5];
    const float* W3 = (const float*)d_in[6];
    const float* b3 = (const float*)d_in[7];
    float* out = (float*)d_out;

    const int N = in_sizes[0] / IN_DIM;     // 100000
    const int E = in_sizes[1] / 2;          // 1600000
    const int* src = ei;
    const int* dst = ei + E;
    const int NC = (N + 255) >> 8;          // 391 coarse buckets
    const int NBLK = (E + EPB - 1) / EPB;   // 391 partition blocks

    // ---- workspace layout ----
    char* w = (char*)d_ws;
    auto alloc = [&](size_t bytes) {
        char* p = w;
        w += (bytes + 1023) & ~(size_t)1023;
        return p;
    };
    float*          dis        = (float*)alloc((size_t)N * 4);
    unsigned short* Hbs        = (unsigned short*)alloc((size_t)N * 64 * 2);
    unsigned short* Hb1        = (unsigned short*)alloc((size_t)N * 64 * 2);
    float*          colS       = (float*)alloc((size_t)N * 4);
    int*            rowStart   = (int*)alloc((size_t)(N + 1) * 4);
    int*            bktTotal   = (int*)alloc((size_t)MAXC * 4);
    int*            coarseStart= (int*)alloc((size_t)(MAXC + 1) * 4);
    int*            hmat       = (int*)alloc((size_t)MAXB * MAXC * 4);
    int*            esrc       = (int*)alloc((size_t)E * 4 + 1024);
    int*            tmp1       = (int*)alloc((size_t)E * 4);
    int*            ctr        = (int*)alloc(64);

    const int NB_N   = (N + 255) / 256;
    const int NB_MX  = (N + 63) / 64;                    // MFMA transform blocks
    const int NB_G8  = (((N + 7) / 8) * 64 + 255) / 256; // 8 nodes per wave
    const int NB_GMX = (N + 31) / 32;                    // 32 nodes per block

    // ---- deterministic partition (4 kernels; cscan folded into bktscan) ----
    k_hist2<<<NBLK, 256, 0, stream>>>(dst, hmat, ctr, E, NC);
    k_bktscan<<<NC, 512, 0, stream>>>(hmat, bktTotal, ctr, coarseStart, rowStart,
                                      NBLK, NC, N, E);
    k_part1<<<NBLK, 256, 0, stream>>>(src, dst, hmat, coarseStart, tmp1, E, NC);
    k_degplace<<<NC, DPT, 0, stream>>>(tmp1, coarseStart, dis, rowStart, esrc, N);

    // ---- layer 1 transform ----
    k_mmx<IN_DIM, float><<<NB_MX, 256, 0, stream>>>(x, W1, dis, Hbs, N);

    // ---- fused: layer-1 gather + layer-2 transform (Hbs -> Hb1, via LDS) ----
    k_gmx<<<NB_GMX, 256, 0, stream>>>(Hbs, esrc, rowStart, dis, b1, W2, Hb1, N);

    // ---- layer-2 gather fused with W3 dot ----
    k_gatherW3<<<NB_G8, 256, 0, stream>>>(Hb1, esrc, rowStart, dis, b2,
                                          W3, b3, colS, out, N);

    // ---- layer 3 aggregation ----
    k_gather1<<<NB_N, 256, 0, stream>>>(colS, esrc, rowStart, dis, out, N);
}